// Round 12
// baseline (526.195 us; speedup 1.0000x reference)
//
#include <hip/hip_runtime.h>
#include <hip/hip_bf16.h>

#define NTHP    512
#define NTHM    256
#define ROWS    16
#define NSTEPS  100
#define PITERS  50
#define LAMBDAV 0.1f

typedef __bf16 bf16x8 __attribute__((ext_vector_type(8)));
typedef float  f32x4  __attribute__((ext_vector_type(4)));

__device__ __forceinline__ float bfbits2f(unsigned short h) {
    unsigned int u = ((unsigned int)h) << 16;
    return __builtin_bit_cast(float, u);
}

// ================= kernel A: invL via power iteration (1 block) ============
// Exact R2-verified structure; writes ws[0]=invL, ws[1]=LAMBDAV*invL.
__global__ __launch_bounds__(NTHP)
void fista_pow(const float* __restrict__ Wg, float* __restrict__ wsf)
{
    __shared__ __align__(16) char wst[65536];     // fp32 W, swizzled
    __shared__ __align__(16) float vf[256];
    __shared__ __align__(16) float up[256];
    __shared__ __align__(16) float uf[64];
    __shared__ float red[16];

    const int tid = threadIdx.x, lane = tid & 63;
    #pragma unroll
    for (int i = 0; i < 8; ++i) {
        int wi = (tid + i * NTHP) * 4; int j = wi >> 6, k = wi & 63;
        f32x4 v = *(const f32x4*)&Wg[wi];
        *(f32x4*)(wst + j * 256 + ((k * 4) ^ ((j & 7) << 4))) = v;
    }
    if (tid < 256) vf[tid] = 0.0625f;
    __syncthreads();
    for (int it = 0; it <= PITERS; ++it) {
        if (tid < 256) {
            int col = tid & 63, jq = tid >> 6;
            float s = 0.f;
            #pragma unroll 4
            for (int j = jq * 64; j < jq * 64 + 64; ++j)
                s += vf[j] * *(const float*)(wst + j * 256 + ((col * 4) ^ ((j & 7) << 4)));
            up[tid] = s;
        }
        __syncthreads();
        if (tid < 64) uf[tid] = up[tid] + up[tid + 64] + up[tid + 128] + up[tid + 192];
        __syncthreads();
        float w2 = 0.f;
        if (tid < 256) {
            float s = 0.f;
            #pragma unroll
            for (int kc = 0; kc < 64; kc += 4) {
                f32x4 wv = *(const f32x4*)(wst + tid * 256 + ((kc * 4) ^ ((tid & 7) << 4)));
                f32x4 u4 = *(const f32x4*)&uf[kc];
                s += wv.x * u4.x + wv.y * u4.y + wv.z * u4.z + wv.w * u4.w;
            }
            w2 = 2.f * s;
        }
        float sq = (tid < 256) ? ((it == PITERS) ? vf[tid] * w2 : w2 * w2) : 0.f;
        #pragma unroll
        for (int off = 32; off >= 1; off >>= 1) sq += __shfl_down(sq, off);
        if (tid < 256 && lane == 0) red[tid >> 6] = sq;
        __syncthreads();
        float tot = red[0] + red[1] + red[2] + red[3];
        if (it < PITERS) { if (tid < 256) vf[tid] = w2 * (1.f / sqrtf(tot)); }
        else if (tid == 0) { wsf[0] = 1.f / tot; wsf[1] = LAMBDAV / tot; }
        __syncthreads();
    }
}

// ================= main kernel: 16-row blocks, 4 waves, 3 blocks/CU ========
// LDS map (53248 B, no overlays):
//   YH bf16 [16][256] @0      stride 512
//   YL bf16 [16][256] @8192   stride 512
//   RH bf16 [16][64]  @16384  stride 128
//   RL bf16 [16][64]  @18432  stride 128
//   WL bf16 [256][64] @20480  stride 128   (p2 A-lo plane, init-once)
// Persistent regs ~116: wbh 32 + wbl 32 + w2h 32 + xm 16 + nin 4.
// y has NO register copy: update reads its own LDS cells back (race-free).
#define YH 0
#define YL 8192
#define RH 16384
#define RL 18432
#define WL 20480

__global__ __launch_bounds__(NTHM)
void fista12(const float* __restrict__ inp, const float* __restrict__ Wg,
             const float* __restrict__ X0, const float* __restrict__ wsf,
             float* __restrict__ out)
{
    __shared__ __align__(16) char lds[53248];

    const int tid  = threadIdx.x;
    const int w    = tid >> 6;        // 0..3
    const int lane = tid & 63;
    const int l4   = lane >> 4;       // 0..3
    const int ln   = lane & 15;       // 0..15
    const int rb   = blockIdx.x * ROWS;
    const int rxl  = (ln & 7) << 4;   // swizzle for all ln-row reads

    const float c2  = 2.f * wsf[0];
    const float thr = wsf[1];

    // ---- p1 B-frags: W[32c+8l4+t][16w+ln] hi+lo -> 16 frags (64 VGPR) ----
    bf16x8 wbh[8], wbl[8];
    #pragma unroll
    for (int c = 0; c < 8; ++c) {
        bf16x8 ph{}, pl{};
        #pragma unroll
        for (int t = 0; t < 8; ++t) {
            float wv = Wg[(32 * c + 8 * l4 + t) * 64 + 16 * w + ln];
            __bf16 h = (__bf16)wv;
            ph[t] = h; pl[t] = (__bf16)(wv - (float)h);
        }
        wbh[c] = ph; wbl[c] = pl;
    }
    // ---- p2 A-hi frags: W[(4w+dt)*16+ln][kc*32+8l4+t] -> 8 frags (32 VGPR) --
    bf16x8 w2h[4][2];
    #pragma unroll
    for (int dt = 0; dt < 4; ++dt) {
        const int row = (4 * w + dt) * 16 + ln;
        #pragma unroll
        for (int kc = 0; kc < 2; ++kc) {
            f32x4 v0 = *(const f32x4*)&Wg[row * 64 + kc * 32 + 8 * l4];
            f32x4 v1 = *(const f32x4*)&Wg[row * 64 + kc * 32 + 8 * l4 + 4];
            bf16x8 p{};
            #pragma unroll
            for (int t = 0; t < 4; ++t) { p[t] = (__bf16)v0[t]; p[4 + t] = (__bf16)v1[t]; }
            w2h[dt][kc] = p;
        }
    }
    // ---- WL plane: W-lo [256][64] (coalesced global read, init-once) ----
    for (int i = tid; i < 256 * 64; i += NTHM) {
        int j = i >> 6, k = i & 63;
        float wv = Wg[i];
        __bf16 h = (__bf16)wv;
        *(__bf16*)(lds + WL + j * 128 + ((k * 2) ^ ((j & 7) << 4))) = (__bf16)(wv - (float)h);
    }

    // ---- per-thread constants ----
    float nin[4];
    #pragma unroll
    for (int r = 0; r < 4; ++r)
        nin[r] = -inp[(size_t)(rb + 4 * l4 + r) * 64 + 16 * w + ln];

    // ---- X0 -> xm regs + y0 LDS planes ----
    float xm[4][4];
    #pragma unroll
    for (int dt = 0; dt < 4; ++dt) {
        f32x4 x = *(const f32x4*)&X0[(size_t)(rb + ln) * 256 + (4 * w + dt) * 16 + 4 * l4];
        unsigned short hb[4], lb[4];
        #pragma unroll
        for (int r = 0; r < 4; ++r) {
            xm[dt][r] = x[r];
            __bf16 h = (__bf16)x[r];
            hb[r] = __builtin_bit_cast(unsigned short, h);
            lb[r] = __builtin_bit_cast(unsigned short, (__bf16)(x[r] - (float)h));
        }
        const int off = ln * 512 + ((((4 * w + dt) * 16 + 4 * l4) * 2) ^ rxl);
        uint2 H, L;
        H.x = hb[0] | ((unsigned)hb[1] << 16); H.y = hb[2] | ((unsigned)hb[3] << 16);
        L.x = lb[0] | ((unsigned)lb[1] << 16); L.y = lb[2] | ((unsigned)lb[3] << 16);
        *(uint2*)(lds + YH + off) = H;
        *(uint2*)(lds + YL + off) = L;
    }
    __syncthreads();

    float tt_ = 1.f;
    for (int step = 0; step < NSTEPS; ++step) {
        // ==== phase 1: R = y W - in (1 tile/wave; 3 accs = 8-deep chains) ====
        f32x4 aA = { nin[0], nin[1], nin[2], nin[3] };
        f32x4 aB = { 0.f, 0.f, 0.f, 0.f };
        f32x4 aC = { 0.f, 0.f, 0.f, 0.f };
        #pragma unroll
        for (int c = 0; c < 8; ++c) {
            const int kb = c * 64 + l4 * 16;
            bf16x8 ah = *(const bf16x8*)(lds + YH + ln * 512 + (kb ^ rxl));
            bf16x8 al = *(const bf16x8*)(lds + YL + ln * 512 + (kb ^ rxl));
            aA = __builtin_amdgcn_mfma_f32_16x16x32_bf16(ah, wbh[c], aA, 0, 0, 0);
            aB = __builtin_amdgcn_mfma_f32_16x16x32_bf16(al, wbh[c], aB, 0, 0, 0);
            aC = __builtin_amdgcn_mfma_f32_16x16x32_bf16(ah, wbl[c], aC, 0, 0, 0);
        }
        f32x4 acc = (aA + aB) + aC;
        #pragma unroll
        for (int r = 0; r < 4; ++r) {
            int row = 4 * l4 + r;
            int off = row * 128 + (((16 * w + ln) * 2) ^ ((row & 7) << 4));
            __bf16 h = (__bf16)acc[r];
            *(__bf16*)(lds + RH + off) = h;
            *(__bf16*)(lds + RL + off) = (__bf16)(acc[r] - (float)h);
        }
        __syncthreads();

        // ==== phase 2: g^T = W R^T (4 dout-tiles/wave, independent accs) ====
        f32x4 gt[4];
        #pragma unroll
        for (int dt = 0; dt < 4; ++dt) gt[dt] = (f32x4){0.f, 0.f, 0.f, 0.f};
        #pragma unroll
        for (int kc = 0; kc < 2; ++kc) {
            const int kb = kc * 64 + l4 * 16;
            bf16x8 bh = *(const bf16x8*)(lds + RH + ln * 128 + (kb ^ rxl));
            bf16x8 bl = *(const bf16x8*)(lds + RL + ln * 128 + (kb ^ rxl));
            #pragma unroll
            for (int dt = 0; dt < 4; ++dt) {
                const int row = (4 * w + dt) * 16 + ln;       // row&7 == ln&7
                bf16x8 al2 = *(const bf16x8*)(lds + WL + row * 128 + (kb ^ rxl));
                gt[dt] = __builtin_amdgcn_mfma_f32_16x16x32_bf16(w2h[dt][kc], bh, gt[dt], 0, 0, 0);
                gt[dt] = __builtin_amdgcn_mfma_f32_16x16x32_bf16(w2h[dt][kc], bl, gt[dt], 0, 0, 0);
                gt[dt] = __builtin_amdgcn_mfma_f32_16x16x32_bf16(al2,         bh, gt[dt], 0, 0, 0);
            }
        }

        // ==== update: read y back (own cells), prox + momentum, write y ====
        const float t2v = 0.5f + 0.5f * sqrtf(1.f + 4.f * tt_ * tt_);
        const float mom = (tt_ - 1.f) / t2v;
        tt_ = t2v;
        #pragma unroll
        for (int dt = 0; dt < 4; ++dt) {
            const int off = ln * 512 + ((((4 * w + dt) * 16 + 4 * l4) * 2) ^ rxl);
            uint2 H = *(const uint2*)(lds + YH + off);
            uint2 L = *(const uint2*)(lds + YL + off);
            float yv[4];
            yv[0] = bfbits2f((unsigned short)H.x) + bfbits2f((unsigned short)L.x);
            yv[1] = bfbits2f((unsigned short)(H.x >> 16)) + bfbits2f((unsigned short)(L.x >> 16));
            yv[2] = bfbits2f((unsigned short)H.y) + bfbits2f((unsigned short)L.y);
            yv[3] = bfbits2f((unsigned short)(H.y >> 16)) + bfbits2f((unsigned short)(L.y >> 16));
            unsigned short hb[4], lb[4];
            #pragma unroll
            for (int r = 0; r < 4; ++r) {
                float u  = yv[r] - c2 * gt[dt][r];
                float x2 = u - fminf(fmaxf(u, -thr), thr);    // prox (exact)
                float yn = x2 + mom * (x2 - xm[dt][r]);
                xm[dt][r] = x2;
                __bf16 h = (__bf16)yn;
                hb[r] = __builtin_bit_cast(unsigned short, h);
                lb[r] = __builtin_bit_cast(unsigned short, (__bf16)(yn - (float)h));
            }
            uint2 Ho, Lo;
            Ho.x = hb[0] | ((unsigned)hb[1] << 16); Ho.y = hb[2] | ((unsigned)hb[3] << 16);
            Lo.x = lb[0] | ((unsigned)lb[1] << 16); Lo.y = lb[2] | ((unsigned)lb[3] << 16);
            *(uint2*)(lds + YH + off) = Ho;
            *(uint2*)(lds + YL + off) = Lo;
        }
        __syncthreads();
    }

    // ---- store X (float4) ----
    #pragma unroll
    for (int dt = 0; dt < 4; ++dt) {
        f32x4 o = { xm[dt][0], xm[dt][1], xm[dt][2], xm[dt][3] };
        *(f32x4*)&out[(size_t)(rb + ln) * 256 + (4 * w + dt) * 16 + 4 * l4] = o;
    }
}

extern "C" void kernel_launch(void* const* d_in, const int* in_sizes, int n_in,
                              void* d_out, int out_size, void* d_ws, size_t ws_size,
                              hipStream_t stream) {
    (void)in_sizes; (void)n_in; (void)ws_size; (void)out_size;
    const float* inp = (const float*)d_in[0];   // [16384, 64]
    const float* Wg  = (const float*)d_in[1];   // [256, 64]
    const float* X0  = (const float*)d_in[2];   // [16384, 256]
    float* outp      = (float*)d_out;           // [16384, 256]
    float* wsf       = (float*)d_ws;            // [invL, thr]
    fista_pow<<<1, NTHP, 0, stream>>>(Wg, wsf);
    fista12<<<16384 / ROWS, NTHM, 0, stream>>>(inp, Wg, X0, wsf, outp);
}

// Round 13
// 463.964 us; speedup vs baseline: 1.1341x; 1.1341x over previous
//
#include <hip/hip_runtime.h>
#include <hip/hip_bf16.h>

#define NTH     256
#define ROWS    16
#define NSTEPS  100
#define PITERS  50
#define LAMBDAV 0.1f

typedef __bf16 bf16x8 __attribute__((ext_vector_type(8)));
typedef float  f32x4  __attribute__((ext_vector_type(4)));

// R13 = R12 main structure + (1) in-block invL via M = W^T W (64x64) with a
// single-wave barrier-free power iteration (no serial pre-kernel: -60us wall),
// (2) y-lo plane dropped (p1 reads halve; exact fp32 ym back in registers),
// (3) launch_bounds(256,3) to keep 3 blocks/CU at the higher register count.
// LDS map (45056 B, 3 blocks/CU):
//   YH bf16 [16][256] @0      8192B  stride 512
//   RH bf16 [16][64]  @8192   2048B  stride 128
//   RL bf16 [16][64]  @10240  2048B  stride 128
//   WL bf16 [256][64] @12288 32768B  stride 128   (p2 A-lo plane)
// Init-only overlays (dead before YH/RH/RL/WL are written):
//   WC fp32 [64][64] @0      16384B  (W chunk for M accumulation)
//   M  fp32 [64][64] @16384  16384B
//   v  fp32 [64]     @32768
// Persistent regs ~132: wbh 32 + wbl 32 + w2h 32 + xm 16 + ym 16 + nin 4.
#define YHo 0
#define RHo 8192
#define RLo 10240
#define WLo 12288
#define WCo 0
#define Mo  16384
#define Vo  32768

__global__ __launch_bounds__(NTH, 3)
void fista13(const float* __restrict__ inp, const float* __restrict__ Wg,
             const float* __restrict__ X0, float* __restrict__ out)
{
    __shared__ __align__(16) char lds[45056];
    __shared__ float scal[2];

    const int tid  = threadIdx.x;
    const int w    = tid >> 6;        // 0..3
    const int lane = tid & 63;
    const int l4   = lane >> 4;       // 0..3
    const int ln   = lane & 15;       // 0..15
    const int rb   = blockIdx.x * ROWS;
    const int rxl  = (ln & 7) << 4;

    // ================= M = W^T W  (4 chunks of 64 W-rows) =================
    {
        const int mi_ = tid >> 4;     // 0..15 -> M rows 4mi_..4mi_+3
        const int mj_ = tid & 15;     //        -> M cols 4mj_..4mj_+3
        f32x4 mac[4];
        #pragma unroll
        for (int r = 0; r < 4; ++r) mac[r] = (f32x4){0.f, 0.f, 0.f, 0.f};
        for (int ch = 0; ch < 4; ++ch) {
            #pragma unroll
            for (int i = 0; i < 4; ++i) {
                int idx = tid + i * NTH;               // f32x4 index, 0..1023
                int kl = idx >> 4, c4 = (idx & 15) * 4;
                f32x4 v = *(const f32x4*)&Wg[(64 * ch + kl) * 64 + c4];
                *(f32x4*)(lds + WCo + kl * 256 + ((c4 * 4) ^ ((kl & 7) << 4))) = v;
            }
            __syncthreads();
            #pragma unroll 8
            for (int k = 0; k < 64; ++k) {
                f32x4 a = *(const f32x4*)(lds + WCo + k * 256 + ((mi_ * 16) ^ ((k & 7) << 4)));
                f32x4 b = *(const f32x4*)(lds + WCo + k * 256 + ((mj_ * 16) ^ ((k & 7) << 4)));
                #pragma unroll
                for (int r = 0; r < 4; ++r) mac[r] += b * a[r];
            }
            __syncthreads();
        }
        #pragma unroll
        for (int r = 0; r < 4; ++r) {
            int m = 4 * mi_ + r;
            *(f32x4*)(lds + Mo + m * 256 + ((mj_ * 16) ^ ((m & 7) << 4))) = mac[r];
        }
    }
    __syncthreads();

    // ====== power iteration on M (wave 0 only, barrier-free) ======
    if (tid < 64) {
        f32x4 Mr[16];
        #pragma unroll
        for (int q = 0; q < 16; ++q)
            Mr[q] = *(const f32x4*)(lds + Mo + tid * 256 + ((q * 16) ^ ((tid & 7) << 4)));
        *(float*)(lds + Vo + tid * 4) = 0.125f;            // ones(64)/8
        for (int it = 0; it <= PITERS; ++it) {
            float a0 = 0.f, a1 = 0.f, a2 = 0.f, a3 = 0.f;
            #pragma unroll
            for (int q = 0; q < 4; ++q) {
                f32x4 v0 = *(const f32x4*)(lds + Vo + (4 * q + 0) * 16);
                f32x4 v1 = *(const f32x4*)(lds + Vo + (4 * q + 1) * 16);
                f32x4 v2 = *(const f32x4*)(lds + Vo + (4 * q + 2) * 16);
                f32x4 v3 = *(const f32x4*)(lds + Vo + (4 * q + 3) * 16);
                a0 += Mr[4*q+0].x*v0.x + Mr[4*q+0].y*v0.y + Mr[4*q+0].z*v0.z + Mr[4*q+0].w*v0.w;
                a1 += Mr[4*q+1].x*v1.x + Mr[4*q+1].y*v1.y + Mr[4*q+1].z*v1.z + Mr[4*q+1].w*v1.w;
                a2 += Mr[4*q+2].x*v2.x + Mr[4*q+2].y*v2.y + Mr[4*q+2].z*v2.z + Mr[4*q+2].w*v2.w;
                a3 += Mr[4*q+3].x*v3.x + Mr[4*q+3].y*v3.y + Mr[4*q+3].z*v3.z + Mr[4*q+3].w*v3.w;
            }
            float mv = (a0 + a1) + (a2 + a3);               // (M v)[tid]
            if (it < PITERS) {
                float n2 = mv * mv;
                #pragma unroll
                for (int off = 32; off >= 1; off >>= 1) n2 += __shfl_xor(n2, off);
                *(float*)(lds + Vo + tid * 4) = mv * (1.f / sqrtf(n2));
            } else {
                float pr = (*(const float*)(lds + Vo + tid * 4)) * mv;   // Rayleigh
                #pragma unroll
                for (int off = 32; off >= 1; off >>= 1) pr += __shfl_xor(pr, off);
                if (tid == 0) {
                    float L = 2.f * pr;                    // lambda(Q)=2*lambda(M)
                    scal[0] = 1.f / L;
                    scal[1] = LAMBDAV / L;
                }
            }
        }
    }
    __syncthreads();   // pow done; M/WC/v regions dead from here on

    const float c2  = 2.f * scal[0];
    const float thr = scal[1];

    // ---- p1 B-frags: W[32c+8l4+t][16w+ln] hi+lo -> 16 frags (64 VGPR) ----
    bf16x8 wbh[8], wbl[8];
    #pragma unroll
    for (int c = 0; c < 8; ++c) {
        bf16x8 ph{}, pl{};
        #pragma unroll
        for (int t = 0; t < 8; ++t) {
            float wv = Wg[(32 * c + 8 * l4 + t) * 64 + 16 * w + ln];
            __bf16 h = (__bf16)wv;
            ph[t] = h; pl[t] = (__bf16)(wv - (float)h);
        }
        wbh[c] = ph; wbl[c] = pl;
    }
    // ---- p2 A-hi frags: W[(4w+dt)*16+ln][kc*32+8l4+t] -> 8 frags (32 VGPR) --
    bf16x8 w2h[4][2];
    #pragma unroll
    for (int dt = 0; dt < 4; ++dt) {
        const int row = (4 * w + dt) * 16 + ln;
        #pragma unroll
        for (int kc = 0; kc < 2; ++kc) {
            f32x4 v0 = *(const f32x4*)&Wg[row * 64 + kc * 32 + 8 * l4];
            f32x4 v1 = *(const f32x4*)&Wg[row * 64 + kc * 32 + 8 * l4 + 4];
            bf16x8 p{};
            #pragma unroll
            for (int t = 0; t < 4; ++t) { p[t] = (__bf16)v0[t]; p[4 + t] = (__bf16)v1[t]; }
            w2h[dt][kc] = p;
        }
    }
    // ---- WL plane: W-lo [256][64] (vectorized, init-once) ----
    #pragma unroll
    for (int i = 0; i < 16; ++i) {
        int i2 = tid + i * NTH;                   // f32x4 index over [256][64]
        int j = i2 >> 4, k4 = (i2 & 15) * 4;
        f32x4 v = *(const f32x4*)&Wg[j * 64 + k4];
        unsigned short b0_ = __builtin_bit_cast(unsigned short, (__bf16)(v.x - (float)(__bf16)v.x));
        unsigned short b1_ = __builtin_bit_cast(unsigned short, (__bf16)(v.y - (float)(__bf16)v.y));
        unsigned short b2_ = __builtin_bit_cast(unsigned short, (__bf16)(v.z - (float)(__bf16)v.z));
        unsigned short b3_ = __builtin_bit_cast(unsigned short, (__bf16)(v.w - (float)(__bf16)v.w));
        uint2 P; P.x = b0_ | ((unsigned)b1_ << 16); P.y = b2_ | ((unsigned)b3_ << 16);
        *(uint2*)(lds + WLo + j * 128 + ((k4 * 2) ^ ((j & 7) << 4))) = P;
    }

    // ---- per-thread constants ----
    float nin[4];
    #pragma unroll
    for (int r = 0; r < 4; ++r)
        nin[r] = -inp[(size_t)(rb + 4 * l4 + r) * 64 + 16 * w + ln];

    // ---- X0 -> xm/ym regs + y0-hi into YH ----
    float xm[4][4], ym[4][4];
    #pragma unroll
    for (int dt = 0; dt < 4; ++dt) {
        f32x4 x = *(const f32x4*)&X0[(size_t)(rb + ln) * 256 + (4 * w + dt) * 16 + 4 * l4];
        unsigned short hb[4];
        #pragma unroll
        for (int r = 0; r < 4; ++r) {
            xm[dt][r] = x[r]; ym[dt][r] = x[r];
            hb[r] = __builtin_bit_cast(unsigned short, (__bf16)x[r]);
        }
        const int off = ln * 512 + ((((4 * w + dt) * 16 + 4 * l4) * 2) ^ rxl);
        uint2 H; H.x = hb[0] | ((unsigned)hb[1] << 16); H.y = hb[2] | ((unsigned)hb[3] << 16);
        *(uint2*)(lds + YHo + off) = H;
    }
    __syncthreads();

    float tt_ = 1.f;
    for (int step = 0; step < NSTEPS; ++step) {
        // ==== phase 1: R = y_h W - in  (2 MFMA per c: hi*Wh + hi*Wl) ====
        f32x4 aA = { nin[0], nin[1], nin[2], nin[3] };
        f32x4 aC = { 0.f, 0.f, 0.f, 0.f };
        #pragma unroll
        for (int c = 0; c < 8; ++c) {
            const int kb = c * 64 + l4 * 16;
            bf16x8 ah = *(const bf16x8*)(lds + YHo + ln * 512 + (kb ^ rxl));
            aA = __builtin_amdgcn_mfma_f32_16x16x32_bf16(ah, wbh[c], aA, 0, 0, 0);
            aC = __builtin_amdgcn_mfma_f32_16x16x32_bf16(ah, wbl[c], aC, 0, 0, 0);
        }
        f32x4 acc = aA + aC;
        #pragma unroll
        for (int r = 0; r < 4; ++r) {
            int row = 4 * l4 + r;
            int off = row * 128 + (((16 * w + ln) * 2) ^ ((row & 7) << 4));
            __bf16 h = (__bf16)acc[r];
            *(__bf16*)(lds + RHo + off) = h;
            *(__bf16*)(lds + RLo + off) = (__bf16)(acc[r] - (float)h);
        }
        __syncthreads();

        // ==== phase 2: g^T = W R^T (4 dout-tiles/wave) ====
        f32x4 gt[4];
        #pragma unroll
        for (int dt = 0; dt < 4; ++dt) gt[dt] = (f32x4){0.f, 0.f, 0.f, 0.f};
        #pragma unroll
        for (int kc = 0; kc < 2; ++kc) {
            const int kb = kc * 64 + l4 * 16;
            bf16x8 bh = *(const bf16x8*)(lds + RHo + ln * 128 + (kb ^ rxl));
            bf16x8 bl = *(const bf16x8*)(lds + RLo + ln * 128 + (kb ^ rxl));
            #pragma unroll
            for (int dt = 0; dt < 4; ++dt) {
                const int row = (4 * w + dt) * 16 + ln;       // row&7 == ln&7
                bf16x8 al2 = *(const bf16x8*)(lds + WLo + row * 128 + (kb ^ rxl));
                gt[dt] = __builtin_amdgcn_mfma_f32_16x16x32_bf16(w2h[dt][kc], bh, gt[dt], 0, 0, 0);
                gt[dt] = __builtin_amdgcn_mfma_f32_16x16x32_bf16(w2h[dt][kc], bl, gt[dt], 0, 0, 0);
                gt[dt] = __builtin_amdgcn_mfma_f32_16x16x32_bf16(al2,         bh, gt[dt], 0, 0, 0);
            }
        }

        // ==== update: prox + momentum (fp32 ym in regs); y-hi b64 writes ====
        const float t2v = 0.5f + 0.5f * sqrtf(1.f + 4.f * tt_ * tt_);
        const float mom = (tt_ - 1.f) / t2v;
        tt_ = t2v;
        #pragma unroll
        for (int dt = 0; dt < 4; ++dt) {
            unsigned short hb[4];
            #pragma unroll
            for (int r = 0; r < 4; ++r) {
                float u  = ym[dt][r] - c2 * gt[dt][r];
                float x2 = u - fminf(fmaxf(u, -thr), thr);    // prox (exact)
                float yn = x2 + mom * (x2 - xm[dt][r]);
                xm[dt][r] = x2; ym[dt][r] = yn;
                hb[r] = __builtin_bit_cast(unsigned short, (__bf16)yn);
            }
            const int off = ln * 512 + ((((4 * w + dt) * 16 + 4 * l4) * 2) ^ rxl);
            uint2 H; H.x = hb[0] | ((unsigned)hb[1] << 16); H.y = hb[2] | ((unsigned)hb[3] << 16);
            *(uint2*)(lds + YHo + off) = H;
        }
        __syncthreads();
    }

    // ---- store X (float4) ----
    #pragma unroll
    for (int dt = 0; dt < 4; ++dt) {
        f32x4 o = { xm[dt][0], xm[dt][1], xm[dt][2], xm[dt][3] };
        *(f32x4*)&out[(size_t)(rb + ln) * 256 + (4 * w + dt) * 16 + 4 * l4] = o;
    }
}

extern "C" void kernel_launch(void* const* d_in, const int* in_sizes, int n_in,
                              void* d_out, int out_size, void* d_ws, size_t ws_size,
                              hipStream_t stream) {
    (void)in_sizes; (void)n_in; (void)d_ws; (void)ws_size; (void)out_size;
    const float* inp = (const float*)d_in[0];   // [16384, 64]
    const float* Wg  = (const float*)d_in[1];   // [256, 64]
    const float* X0  = (const float*)d_in[2];   // [16384, 256]
    float* outp      = (float*)d_out;           // [16384, 256]
    fista13<<<16384 / ROWS, NTH, 0, stream>>>(inp, Wg, X0, outp);
}

// Round 14
// 379.831 us; speedup vs baseline: 1.3853x; 1.2215x over previous
//
#include <hip/hip_runtime.h>
#include <hip/hip_bf16.h>

#define NTH     256
#define ROWS    16
#define NSTEPS  100
#define PITERS  50
#define LAMBDAV 0.1f

typedef __bf16 bf16x8 __attribute__((ext_vector_type(8)));
typedef float  f32x4  __attribute__((ext_vector_type(4)));

// R14 = R13 + (1) p2 third product (Wl*Rh) dropped -> WL plane deleted
// (p2 reads 12->4 b128/wave, MFMA 24->16), (2) pow reads M from LDS (no
// Mr[16] regs -> kills R13's init spill, WRITE_SIZE 48->17MB predicted),
// (3) M overlays WC (dead) -> LDS 45.5K -> 16.6KB; registers gate residency.
// LDS map (16640 B):
//   main:  YH bf16 [16][256] @0 (8192)  RH @8192 (2048)  RL @10240 (2048)
//   init:  WC fp32 [64][64] @0 (16384); M fp32 [64][64] @0 (overlays WC after
//          its last read); v fp32[64] @16384. YH/RH/RL written only after pow.
// Persistent regs ~132: wbh 32 + wbl 32 + w2h 32 + xm 16 + ym 16 + nin 4.
#define YHo 0
#define RHo 8192
#define RLo 10240
#define WCo 0
#define Mo  0
#define Vo  16384

__global__ __launch_bounds__(NTH, 3)
void fista14(const float* __restrict__ inp, const float* __restrict__ Wg,
             const float* __restrict__ X0, float* __restrict__ out)
{
    __shared__ __align__(16) char lds[16640];
    __shared__ float scal[2];

    const int tid  = threadIdx.x;
    const int w    = tid >> 6;        // 0..3
    const int lane = tid & 63;
    const int l4   = lane >> 4;       // 0..3
    const int ln   = lane & 15;       // 0..15
    const int rb   = blockIdx.x * ROWS;
    const int rxl  = (ln & 7) << 4;

    // ================= M = W^T W  (4 chunks of 64 W-rows) =================
    {
        const int mi_ = tid >> 4;     // M rows 4mi_..4mi_+3
        const int mj_ = tid & 15;     // M cols 4mj_..4mj_+3
        f32x4 mac[4];
        #pragma unroll
        for (int r = 0; r < 4; ++r) mac[r] = (f32x4){0.f, 0.f, 0.f, 0.f};
        for (int ch = 0; ch < 4; ++ch) {
            #pragma unroll
            for (int i = 0; i < 4; ++i) {
                int idx = tid + i * NTH;               // f32x4 index, 0..1023
                int kl = idx >> 4, c4 = (idx & 15) * 4;
                f32x4 v = *(const f32x4*)&Wg[(64 * ch + kl) * 64 + c4];
                *(f32x4*)(lds + WCo + kl * 256 + ((c4 * 4) ^ ((kl & 7) << 4))) = v;
            }
            __syncthreads();
            #pragma unroll 8
            for (int k = 0; k < 64; ++k) {
                f32x4 a = *(const f32x4*)(lds + WCo + k * 256 + ((mi_ * 16) ^ ((k & 7) << 4)));
                f32x4 b = *(const f32x4*)(lds + WCo + k * 256 + ((mj_ * 16) ^ ((k & 7) << 4)));
                #pragma unroll
                for (int r = 0; r < 4; ++r) mac[r] += b * a[r];
            }
            __syncthreads();          // WC chunk consumed (last iter: WC dead)
        }
        #pragma unroll
        for (int r = 0; r < 4; ++r) {
            int m = 4 * mi_ + r;
            *(f32x4*)(lds + Mo + m * 256 + ((mj_ * 16) ^ ((m & 7) << 4))) = mac[r];
        }
    }
    __syncthreads();

    // ====== power iteration on M (wave 0; M read from LDS — no Mr regs) ======
    if (tid < 64) {
        const int xsw = (tid & 7) << 4;
        *(float*)(lds + Vo + tid * 4) = 0.125f;            // ones(64)/8
        for (int it = 0; it <= PITERS; ++it) {
            float a0 = 0.f, a1 = 0.f, a2 = 0.f, a3 = 0.f;
            #pragma unroll
            for (int q = 0; q < 4; ++q) {
                f32x4 m0 = *(const f32x4*)(lds + Mo + tid * 256 + (((4 * q + 0) * 16) ^ xsw));
                f32x4 m1 = *(const f32x4*)(lds + Mo + tid * 256 + (((4 * q + 1) * 16) ^ xsw));
                f32x4 m2 = *(const f32x4*)(lds + Mo + tid * 256 + (((4 * q + 2) * 16) ^ xsw));
                f32x4 m3 = *(const f32x4*)(lds + Mo + tid * 256 + (((4 * q + 3) * 16) ^ xsw));
                f32x4 v0 = *(const f32x4*)(lds + Vo + (4 * q + 0) * 16);
                f32x4 v1 = *(const f32x4*)(lds + Vo + (4 * q + 1) * 16);
                f32x4 v2 = *(const f32x4*)(lds + Vo + (4 * q + 2) * 16);
                f32x4 v3 = *(const f32x4*)(lds + Vo + (4 * q + 3) * 16);
                a0 += m0.x * v0.x + m0.y * v0.y + m0.z * v0.z + m0.w * v0.w;
                a1 += m1.x * v1.x + m1.y * v1.y + m1.z * v1.z + m1.w * v1.w;
                a2 += m2.x * v2.x + m2.y * v2.y + m2.z * v2.z + m2.w * v2.w;
                a3 += m3.x * v3.x + m3.y * v3.y + m3.z * v3.z + m3.w * v3.w;
            }
            float mv = (a0 + a1) + (a2 + a3);               // (M v)[tid]
            if (it < PITERS) {
                float n2 = mv * mv;
                #pragma unroll
                for (int off = 32; off >= 1; off >>= 1) n2 += __shfl_xor(n2, off);
                *(float*)(lds + Vo + tid * 4) = mv * (1.f / sqrtf(n2));
            } else {
                float pr = (*(const float*)(lds + Vo + tid * 4)) * mv;   // Rayleigh
                #pragma unroll
                for (int off = 32; off >= 1; off >>= 1) pr += __shfl_xor(pr, off);
                if (tid == 0) {
                    float L = 2.f * pr;                    // lambda(Q)=2*lambda(M)
                    scal[0] = 1.f / L;
                    scal[1] = LAMBDAV / L;
                }
            }
        }
    }
    __syncthreads();   // pow done; M/v regions dead from here on

    const float c2  = 2.f * scal[0];
    const float thr = scal[1];

    // ---- p1 B-frags: W[32c+8l4+t][16w+ln] hi+lo -> 16 frags (64 VGPR) ----
    bf16x8 wbh[8], wbl[8];
    #pragma unroll
    for (int c = 0; c < 8; ++c) {
        bf16x8 ph{}, pl{};
        #pragma unroll
        for (int t = 0; t < 8; ++t) {
            float wv = Wg[(32 * c + 8 * l4 + t) * 64 + 16 * w + ln];
            __bf16 h = (__bf16)wv;
            ph[t] = h; pl[t] = (__bf16)(wv - (float)h);
        }
        wbh[c] = ph; wbl[c] = pl;
    }
    // ---- p2 A-hi frags: W[(4w+dt)*16+ln][kc*32+8l4+t] -> 8 frags (32 VGPR) --
    bf16x8 w2h[4][2];
    #pragma unroll
    for (int dt = 0; dt < 4; ++dt) {
        const int row = (4 * w + dt) * 16 + ln;
        #pragma unroll
        for (int kc = 0; kc < 2; ++kc) {
            f32x4 v0 = *(const f32x4*)&Wg[row * 64 + kc * 32 + 8 * l4];
            f32x4 v1 = *(const f32x4*)&Wg[row * 64 + kc * 32 + 8 * l4 + 4];
            bf16x8 p{};
            #pragma unroll
            for (int t = 0; t < 4; ++t) { p[t] = (__bf16)v0[t]; p[4 + t] = (__bf16)v1[t]; }
            w2h[dt][kc] = p;
        }
    }

    // ---- per-thread constants ----
    float nin[4];
    #pragma unroll
    for (int r = 0; r < 4; ++r)
        nin[r] = -inp[(size_t)(rb + 4 * l4 + r) * 64 + 16 * w + ln];

    // ---- X0 -> xm/ym regs + y0-hi into YH ----
    float xm[4][4], ym[4][4];
    #pragma unroll
    for (int dt = 0; dt < 4; ++dt) {
        f32x4 x = *(const f32x4*)&X0[(size_t)(rb + ln) * 256 + (4 * w + dt) * 16 + 4 * l4];
        unsigned short hb[4];
        #pragma unroll
        for (int r = 0; r < 4; ++r) {
            xm[dt][r] = x[r]; ym[dt][r] = x[r];
            hb[r] = __builtin_bit_cast(unsigned short, (__bf16)x[r]);
        }
        const int off = ln * 512 + ((((4 * w + dt) * 16 + 4 * l4) * 2) ^ rxl);
        uint2 H; H.x = hb[0] | ((unsigned)hb[1] << 16); H.y = hb[2] | ((unsigned)hb[3] << 16);
        *(uint2*)(lds + YHo + off) = H;
    }
    __syncthreads();

    float tt_ = 1.f;
    for (int step = 0; step < NSTEPS; ++step) {
        // ==== phase 1: R = y_h W - in  (2 MFMA per c: hi*Wh + hi*Wl) ====
        f32x4 aA = { nin[0], nin[1], nin[2], nin[3] };
        f32x4 aC = { 0.f, 0.f, 0.f, 0.f };
        #pragma unroll
        for (int c = 0; c < 8; ++c) {
            const int kb = c * 64 + l4 * 16;
            bf16x8 ah = *(const bf16x8*)(lds + YHo + ln * 512 + (kb ^ rxl));
            aA = __builtin_amdgcn_mfma_f32_16x16x32_bf16(ah, wbh[c], aA, 0, 0, 0);
            aC = __builtin_amdgcn_mfma_f32_16x16x32_bf16(ah, wbl[c], aC, 0, 0, 0);
        }
        f32x4 acc = aA + aC;
        #pragma unroll
        for (int r = 0; r < 4; ++r) {
            int row = 4 * l4 + r;
            int off = row * 128 + (((16 * w + ln) * 2) ^ ((row & 7) << 4));
            __bf16 h = (__bf16)acc[r];
            *(__bf16*)(lds + RHo + off) = h;
            *(__bf16*)(lds + RLo + off) = (__bf16)(acc[r] - (float)h);
        }
        __syncthreads();

        // ==== phase 2: g^T = Wh R^T (2 products: Wh*Rh + Wh*Rl) ====
        f32x4 gt[4];
        #pragma unroll
        for (int dt = 0; dt < 4; ++dt) gt[dt] = (f32x4){0.f, 0.f, 0.f, 0.f};
        #pragma unroll
        for (int kc = 0; kc < 2; ++kc) {
            const int kb = kc * 64 + l4 * 16;
            bf16x8 bh = *(const bf16x8*)(lds + RHo + ln * 128 + (kb ^ rxl));
            bf16x8 bl = *(const bf16x8*)(lds + RLo + ln * 128 + (kb ^ rxl));
            #pragma unroll
            for (int dt = 0; dt < 4; ++dt) {
                gt[dt] = __builtin_amdgcn_mfma_f32_16x16x32_bf16(w2h[dt][kc], bh, gt[dt], 0, 0, 0);
                gt[dt] = __builtin_amdgcn_mfma_f32_16x16x32_bf16(w2h[dt][kc], bl, gt[dt], 0, 0, 0);
            }
        }

        // ==== update: prox + momentum (fp32 ym in regs); y-hi b64 writes ====
        const float t2v = 0.5f + 0.5f * sqrtf(1.f + 4.f * tt_ * tt_);
        const float mom = (tt_ - 1.f) / t2v;
        tt_ = t2v;
        #pragma unroll
        for (int dt = 0; dt < 4; ++dt) {
            unsigned short hb[4];
            #pragma unroll
            for (int r = 0; r < 4; ++r) {
                float u  = ym[dt][r] - c2 * gt[dt][r];
                float x2 = u - fminf(fmaxf(u, -thr), thr);    // prox (exact)
                float yn = x2 + mom * (x2 - xm[dt][r]);
                xm[dt][r] = x2; ym[dt][r] = yn;
                hb[r] = __builtin_bit_cast(unsigned short, (__bf16)yn);
            }
            const int off = ln * 512 + ((((4 * w + dt) * 16 + 4 * l4) * 2) ^ rxl);
            uint2 H; H.x = hb[0] | ((unsigned)hb[1] << 16); H.y = hb[2] | ((unsigned)hb[3] << 16);
            *(uint2*)(lds + YHo + off) = H;
        }
        __syncthreads();
    }

    // ---- store X (float4) ----
    #pragma unroll
    for (int dt = 0; dt < 4; ++dt) {
        f32x4 o = { xm[dt][0], xm[dt][1], xm[dt][2], xm[dt][3] };
        *(f32x4*)&out[(size_t)(rb + ln) * 256 + (4 * w + dt) * 16 + 4 * l4] = o;
    }
}

extern "C" void kernel_launch(void* const* d_in, const int* in_sizes, int n_in,
                              void* d_out, int out_size, void* d_ws, size_t ws_size,
                              hipStream_t stream) {
    (void)in_sizes; (void)n_in; (void)d_ws; (void)ws_size; (void)out_size;
    const float* inp = (const float*)d_in[0];   // [16384, 64]
    const float* Wg  = (const float*)d_in[1];   // [256, 64]
    const float* X0  = (const float*)d_in[2];   // [16384, 256]
    float* outp      = (float*)d_out;           // [16384, 256]
    fista14<<<16384 / ROWS, NTH, 0, stream>>>(inp, Wg, X0, outp);
}

// Round 15
// 364.210 us; speedup vs baseline: 1.4448x; 1.0429x over previous
//
#include <hip/hip_runtime.h>
#include <hip/hip_bf16.h>

#define NTH     256
#define ROWS    16
#define NSTEPS  100
#define PITERS  50
#define LAMBDAV 0.1f

typedef __bf16 bf16x8 __attribute__((ext_vector_type(8)));
typedef float  f32x4  __attribute__((ext_vector_type(4)));

// R15 = R14 + p2 W-hi fragments moved from registers (32 unified regs) to an
// LDS plane WH [256][64] (+32KB -> 45.3KB/block, 3 blocks = 136K LDS).
// Probe: if R14 was register-capped at 2 blocks/CU (unified VGPR+AGPR ~170+),
// this buys 3-block residency (+50% waves). If R14 was already 3-resident,
// cost is bounded: p2 reads 4->12 b128/wave-step (~-5%).
// LDS map (45312 B):
//   main: YH bf16 [16][256] @0 (8192)  RH @8192 (2048)  RL @10240 (2048)
//         WH bf16 [256][64] @12288 (32768)  stride 128
//   init overlays (all dead before YH/RH/RL/WH are written):
//         WC fp32 [64][64] @0 (16384); M fp32 [64][64] @0; v fp32[64] @45056
// Persistent regs ~: wbh 32 + wbl 32 + xm 16 + ym 16 + nin 4 (w2h deleted).
#define YHo 0
#define RHo 8192
#define RLo 10240
#define WHo 12288
#define WCo 0
#define Mo  0
#define Vo  45056

__global__ __launch_bounds__(NTH, 3)
void fista15(const float* __restrict__ inp, const float* __restrict__ Wg,
             const float* __restrict__ X0, float* __restrict__ out)
{
    __shared__ __align__(16) char lds[45312];
    __shared__ float scal[2];

    const int tid  = threadIdx.x;
    const int w    = tid >> 6;        // 0..3
    const int lane = tid & 63;
    const int l4   = lane >> 4;       // 0..3
    const int ln   = lane & 15;       // 0..15
    const int rb   = blockIdx.x * ROWS;
    const int rxl  = (ln & 7) << 4;

    // ================= M = W^T W  (4 chunks of 64 W-rows) =================
    {
        const int mi_ = tid >> 4;     // M rows 4mi_..4mi_+3
        const int mj_ = tid & 15;     // M cols 4mj_..4mj_+3
        f32x4 mac[4];
        #pragma unroll
        for (int r = 0; r < 4; ++r) mac[r] = (f32x4){0.f, 0.f, 0.f, 0.f};
        for (int ch = 0; ch < 4; ++ch) {
            #pragma unroll
            for (int i = 0; i < 4; ++i) {
                int idx = tid + i * NTH;               // f32x4 index, 0..1023
                int kl = idx >> 4, c4 = (idx & 15) * 4;
                f32x4 v = *(const f32x4*)&Wg[(64 * ch + kl) * 64 + c4];
                *(f32x4*)(lds + WCo + kl * 256 + ((c4 * 4) ^ ((kl & 7) << 4))) = v;
            }
            __syncthreads();
            #pragma unroll 8
            for (int k = 0; k < 64; ++k) {
                f32x4 a = *(const f32x4*)(lds + WCo + k * 256 + ((mi_ * 16) ^ ((k & 7) << 4)));
                f32x4 b = *(const f32x4*)(lds + WCo + k * 256 + ((mj_ * 16) ^ ((k & 7) << 4)));
                #pragma unroll
                for (int r = 0; r < 4; ++r) mac[r] += b * a[r];
            }
            __syncthreads();          // WC chunk consumed (last iter: WC dead)
        }
        #pragma unroll
        for (int r = 0; r < 4; ++r) {
            int m = 4 * mi_ + r;
            *(f32x4*)(lds + Mo + m * 256 + ((mj_ * 16) ^ ((m & 7) << 4))) = mac[r];
        }
    }
    __syncthreads();

    // ====== power iteration on M (wave 0; M read from LDS — no Mr regs) ======
    if (tid < 64) {
        const int xsw = (tid & 7) << 4;
        *(float*)(lds + Vo + tid * 4) = 0.125f;            // ones(64)/8
        for (int it = 0; it <= PITERS; ++it) {
            float a0 = 0.f, a1 = 0.f, a2 = 0.f, a3 = 0.f;
            #pragma unroll
            for (int q = 0; q < 4; ++q) {
                f32x4 m0 = *(const f32x4*)(lds + Mo + tid * 256 + (((4 * q + 0) * 16) ^ xsw));
                f32x4 m1 = *(const f32x4*)(lds + Mo + tid * 256 + (((4 * q + 1) * 16) ^ xsw));
                f32x4 m2 = *(const f32x4*)(lds + Mo + tid * 256 + (((4 * q + 2) * 16) ^ xsw));
                f32x4 m3 = *(const f32x4*)(lds + Mo + tid * 256 + (((4 * q + 3) * 16) ^ xsw));
                f32x4 v0 = *(const f32x4*)(lds + Vo + (4 * q + 0) * 16);
                f32x4 v1 = *(const f32x4*)(lds + Vo + (4 * q + 1) * 16);
                f32x4 v2 = *(const f32x4*)(lds + Vo + (4 * q + 2) * 16);
                f32x4 v3 = *(const f32x4*)(lds + Vo + (4 * q + 3) * 16);
                a0 += m0.x * v0.x + m0.y * v0.y + m0.z * v0.z + m0.w * v0.w;
                a1 += m1.x * v1.x + m1.y * v1.y + m1.z * v1.z + m1.w * v1.w;
                a2 += m2.x * v2.x + m2.y * v2.y + m2.z * v2.z + m2.w * v2.w;
                a3 += m3.x * v3.x + m3.y * v3.y + m3.z * v3.z + m3.w * v3.w;
            }
            float mv = (a0 + a1) + (a2 + a3);               // (M v)[tid]
            if (it < PITERS) {
                float n2 = mv * mv;
                #pragma unroll
                for (int off = 32; off >= 1; off >>= 1) n2 += __shfl_xor(n2, off);
                *(float*)(lds + Vo + tid * 4) = mv * (1.f / sqrtf(n2));
            } else {
                float pr = (*(const float*)(lds + Vo + tid * 4)) * mv;   // Rayleigh
                #pragma unroll
                for (int off = 32; off >= 1; off >>= 1) pr += __shfl_xor(pr, off);
                if (tid == 0) {
                    float L = 2.f * pr;                    // lambda(Q)=2*lambda(M)
                    scal[0] = 1.f / L;
                    scal[1] = LAMBDAV / L;
                }
            }
        }
    }
    __syncthreads();   // pow done; M/WC/v regions dead from here on

    const float c2  = 2.f * scal[0];
    const float thr = scal[1];

    // ---- WH plane: W-hi [256][64] bf16 (vectorized, init-once) ----
    #pragma unroll
    for (int i = 0; i < 16; ++i) {
        int i2 = tid + i * NTH;                   // f32x4 index over [256][64]
        int j = i2 >> 4, k4 = (i2 & 15) * 4;
        f32x4 v = *(const f32x4*)&Wg[j * 64 + k4];
        unsigned short h0 = __builtin_bit_cast(unsigned short, (__bf16)v.x);
        unsigned short h1 = __builtin_bit_cast(unsigned short, (__bf16)v.y);
        unsigned short h2 = __builtin_bit_cast(unsigned short, (__bf16)v.z);
        unsigned short h3 = __builtin_bit_cast(unsigned short, (__bf16)v.w);
        uint2 P; P.x = h0 | ((unsigned)h1 << 16); P.y = h2 | ((unsigned)h3 << 16);
        *(uint2*)(lds + WHo + j * 128 + ((k4 * 2) ^ ((j & 7) << 4))) = P;
    }

    // ---- p1 B-frags: W[32c+8l4+t][16w+ln] hi+lo -> 16 frags (64 VGPR) ----
    bf16x8 wbh[8], wbl[8];
    #pragma unroll
    for (int c = 0; c < 8; ++c) {
        bf16x8 ph{}, pl{};
        #pragma unroll
        for (int t = 0; t < 8; ++t) {
            float wv = Wg[(32 * c + 8 * l4 + t) * 64 + 16 * w + ln];
            __bf16 h = (__bf16)wv;
            ph[t] = h; pl[t] = (__bf16)(wv - (float)h);
        }
        wbh[c] = ph; wbl[c] = pl;
    }

    // ---- per-thread constants ----
    float nin[4];
    #pragma unroll
    for (int r = 0; r < 4; ++r)
        nin[r] = -inp[(size_t)(rb + 4 * l4 + r) * 64 + 16 * w + ln];

    // ---- X0 -> xm/ym regs + y0-hi into YH ----
    float xm[4][4], ym[4][4];
    #pragma unroll
    for (int dt = 0; dt < 4; ++dt) {
        f32x4 x = *(const f32x4*)&X0[(size_t)(rb + ln) * 256 + (4 * w + dt) * 16 + 4 * l4];
        unsigned short hb[4];
        #pragma unroll
        for (int r = 0; r < 4; ++r) {
            xm[dt][r] = x[r]; ym[dt][r] = x[r];
            hb[r] = __builtin_bit_cast(unsigned short, (__bf16)x[r]);
        }
        const int off = ln * 512 + ((((4 * w + dt) * 16 + 4 * l4) * 2) ^ rxl);
        uint2 H; H.x = hb[0] | ((unsigned)hb[1] << 16); H.y = hb[2] | ((unsigned)hb[3] << 16);
        *(uint2*)(lds + YHo + off) = H;
    }
    __syncthreads();

    float tt_ = 1.f;
    for (int step = 0; step < NSTEPS; ++step) {
        // ==== phase 1: R = y_h W - in  (2 MFMA per c: hi*Wh + hi*Wl) ====
        f32x4 aA = { nin[0], nin[1], nin[2], nin[3] };
        f32x4 aC = { 0.f, 0.f, 0.f, 0.f };
        #pragma unroll
        for (int c = 0; c < 8; ++c) {
            const int kb = c * 64 + l4 * 16;
            bf16x8 ah = *(const bf16x8*)(lds + YHo + ln * 512 + (kb ^ rxl));
            aA = __builtin_amdgcn_mfma_f32_16x16x32_bf16(ah, wbh[c], aA, 0, 0, 0);
            aC = __builtin_amdgcn_mfma_f32_16x16x32_bf16(ah, wbl[c], aC, 0, 0, 0);
        }
        f32x4 acc = aA + aC;
        #pragma unroll
        for (int r = 0; r < 4; ++r) {
            int row = 4 * l4 + r;
            int off = row * 128 + (((16 * w + ln) * 2) ^ ((row & 7) << 4));
            __bf16 h = (__bf16)acc[r];
            *(__bf16*)(lds + RHo + off) = h;
            *(__bf16*)(lds + RLo + off) = (__bf16)(acc[r] - (float)h);
        }
        __syncthreads();

        // ==== phase 2: g^T = Wh R^T (A-frags from WH plane) ====
        f32x4 gt[4];
        #pragma unroll
        for (int dt = 0; dt < 4; ++dt) gt[dt] = (f32x4){0.f, 0.f, 0.f, 0.f};
        #pragma unroll
        for (int kc = 0; kc < 2; ++kc) {
            const int kb = kc * 64 + l4 * 16;
            bf16x8 bh = *(const bf16x8*)(lds + RHo + ln * 128 + (kb ^ rxl));
            bf16x8 bl = *(const bf16x8*)(lds + RLo + ln * 128 + (kb ^ rxl));
            #pragma unroll
            for (int dt = 0; dt < 4; ++dt) {
                const int row = (4 * w + dt) * 16 + ln;       // row&7 == ln&7
                bf16x8 ah2 = *(const bf16x8*)(lds + WHo + row * 128 + (kb ^ rxl));
                gt[dt] = __builtin_amdgcn_mfma_f32_16x16x32_bf16(ah2, bh, gt[dt], 0, 0, 0);
                gt[dt] = __builtin_amdgcn_mfma_f32_16x16x32_bf16(ah2, bl, gt[dt], 0, 0, 0);
            }
        }

        // ==== update: prox + momentum (fp32 ym in regs); y-hi b64 writes ====
        const float t2v = 0.5f + 0.5f * sqrtf(1.f + 4.f * tt_ * tt_);
        const float mom = (tt_ - 1.f) / t2v;
        tt_ = t2v;
        #pragma unroll
        for (int dt = 0; dt < 4; ++dt) {
            unsigned short hb[4];
            #pragma unroll
            for (int r = 0; r < 4; ++r) {
                float u  = ym[dt][r] - c2 * gt[dt][r];
                float x2 = u - fminf(fmaxf(u, -thr), thr);    // prox (exact)
                float yn = x2 + mom * (x2 - xm[dt][r]);
                xm[dt][r] = x2; ym[dt][r] = yn;
                hb[r] = __builtin_bit_cast(unsigned short, (__bf16)yn);
            }
            const int off = ln * 512 + ((((4 * w + dt) * 16 + 4 * l4) * 2) ^ rxl);
            uint2 H; H.x = hb[0] | ((unsigned)hb[1] << 16); H.y = hb[2] | ((unsigned)hb[3] << 16);
            *(uint2*)(lds + YHo + off) = H;
        }
        __syncthreads();
    }

    // ---- store X (float4) ----
    #pragma unroll
    for (int dt = 0; dt < 4; ++dt) {
        f32x4 o = { xm[dt][0], xm[dt][1], xm[dt][2], xm[dt][3] };
        *(f32x4*)&out[(size_t)(rb + ln) * 256 + (4 * w + dt) * 16 + 4 * l4] = o;
    }
}

extern "C" void kernel_launch(void* const* d_in, const int* in_sizes, int n_in,
                              void* d_out, int out_size, void* d_ws, size_t ws_size,
                              hipStream_t stream) {
    (void)in_sizes; (void)n_in; (void)d_ws; (void)ws_size; (void)out_size;
    const float* inp = (const float*)d_in[0];   // [16384, 64]
    const float* Wg  = (const float*)d_in[1];   // [256, 64]
    const float* X0  = (const float*)d_in[2];   // [16384, 256]
    float* outp      = (float*)d_out;           // [16384, 256]
    fista15<<<16384 / ROWS, NTH, 0, stream>>>(inp, Wg, X0, outp);
}

// Round 16
// 291.386 us; speedup vs baseline: 1.8058x; 1.2499x over previous
//
#include <hip/hip_runtime.h>
#include <hip/hip_bf16.h>

#define NTH     256
#define ROWS    32
#define NSTEPS  100
#define PITERS  50
#define LAMBDAV 0.1f

typedef __bf16 bf16x8 __attribute__((ext_vector_type(8)));
typedef float  f32x4  __attribute__((ext_vector_type(4)));

// R16 = R15 numerics (byte-identical products/rounding) with uniform
// residency: ROWS=32, grid 512 = exactly 2 blocks/CU, ONE round, no ragged
// tail (R15: 1024 blocks at 3-resident -> [37.5% then 12.5%] avg 25%).
// Per wave: 2 m-tiles in p1 (W-frags reused 2x), 2 row-tiles in p2 (WH
// A-frags reused 2x) -> per-unit-work DS reads -23%, barriers/row halved.
// LDS map (57600 B, 2 blocks/CU = 115K):
//   YH bf16 [32][256] @0     (16384) stride 512
//   RH bf16 [32][64]  @16384 (4096)  stride 128
//   RL bf16 [32][64]  @20480 (4096)  stride 128
//   WH bf16 [256][64] @24576 (32768) stride 128
//   init overlays: WC fp32 [64][64] @0 (16384, inside YH); M @0 after WC dead;
//                  v fp32[64] @57344
// Persistent regs ~136: wbh 32 + wbl 32 + xm 32 + ym 32 + nin 8 (R9-proven).
#define YHo 0
#define RHo 16384
#define RLo 20480
#define WHo 24576
#define WCo 0
#define Mo  0
#define Vo  57344

__global__ __launch_bounds__(NTH, 2)
void fista16(const float* __restrict__ inp, const float* __restrict__ Wg,
             const float* __restrict__ X0, float* __restrict__ out)
{
    __shared__ __align__(16) char lds[57600];
    __shared__ float scal[2];

    const int tid  = threadIdx.x;
    const int w    = tid >> 6;        // 0..3
    const int lane = tid & 63;
    const int l4   = lane >> 4;       // 0..3
    const int ln   = lane & 15;       // 0..15
    const int rb   = blockIdx.x * ROWS;
    const int rxl  = (ln & 7) << 4;

    // ================= M = W^T W  (4 chunks of 64 W-rows) =================
    {
        const int mi_ = tid >> 4;     // M rows 4mi_..4mi_+3
        const int mj_ = tid & 15;     // M cols 4mj_..4mj_+3
        f32x4 mac[4];
        #pragma unroll
        for (int r = 0; r < 4; ++r) mac[r] = (f32x4){0.f, 0.f, 0.f, 0.f};
        for (int ch = 0; ch < 4; ++ch) {
            #pragma unroll
            for (int i = 0; i < 4; ++i) {
                int idx = tid + i * NTH;               // f32x4 index, 0..1023
                int kl = idx >> 4, c4 = (idx & 15) * 4;
                f32x4 v = *(const f32x4*)&Wg[(64 * ch + kl) * 64 + c4];
                *(f32x4*)(lds + WCo + kl * 256 + ((c4 * 4) ^ ((kl & 7) << 4))) = v;
            }
            __syncthreads();
            #pragma unroll 8
            for (int k = 0; k < 64; ++k) {
                f32x4 a = *(const f32x4*)(lds + WCo + k * 256 + ((mi_ * 16) ^ ((k & 7) << 4)));
                f32x4 b = *(const f32x4*)(lds + WCo + k * 256 + ((mj_ * 16) ^ ((k & 7) << 4)));
                #pragma unroll
                for (int r = 0; r < 4; ++r) mac[r] += b * a[r];
            }
            __syncthreads();          // WC chunk consumed (last iter: WC dead)
        }
        #pragma unroll
        for (int r = 0; r < 4; ++r) {
            int m = 4 * mi_ + r;
            *(f32x4*)(lds + Mo + m * 256 + ((mj_ * 16) ^ ((m & 7) << 4))) = mac[r];
        }
    }
    __syncthreads();

    // ====== power iteration on M (wave 0; M read from LDS) ======
    if (tid < 64) {
        const int xsw = (tid & 7) << 4;
        *(float*)(lds + Vo + tid * 4) = 0.125f;            // ones(64)/8
        for (int it = 0; it <= PITERS; ++it) {
            float a0 = 0.f, a1 = 0.f, a2 = 0.f, a3 = 0.f;
            #pragma unroll
            for (int q = 0; q < 4; ++q) {
                f32x4 m0 = *(const f32x4*)(lds + Mo + tid * 256 + (((4 * q + 0) * 16) ^ xsw));
                f32x4 m1 = *(const f32x4*)(lds + Mo + tid * 256 + (((4 * q + 1) * 16) ^ xsw));
                f32x4 m2 = *(const f32x4*)(lds + Mo + tid * 256 + (((4 * q + 2) * 16) ^ xsw));
                f32x4 m3 = *(const f32x4*)(lds + Mo + tid * 256 + (((4 * q + 3) * 16) ^ xsw));
                f32x4 v0 = *(const f32x4*)(lds + Vo + (4 * q + 0) * 16);
                f32x4 v1 = *(const f32x4*)(lds + Vo + (4 * q + 1) * 16);
                f32x4 v2 = *(const f32x4*)(lds + Vo + (4 * q + 2) * 16);
                f32x4 v3 = *(const f32x4*)(lds + Vo + (4 * q + 3) * 16);
                a0 += m0.x * v0.x + m0.y * v0.y + m0.z * v0.z + m0.w * v0.w;
                a1 += m1.x * v1.x + m1.y * v1.y + m1.z * v1.z + m1.w * v1.w;
                a2 += m2.x * v2.x + m2.y * v2.y + m2.z * v2.z + m2.w * v2.w;
                a3 += m3.x * v3.x + m3.y * v3.y + m3.z * v3.z + m3.w * v3.w;
            }
            float mv = (a0 + a1) + (a2 + a3);               // (M v)[tid]
            if (it < PITERS) {
                float n2 = mv * mv;
                #pragma unroll
                for (int off = 32; off >= 1; off >>= 1) n2 += __shfl_xor(n2, off);
                *(float*)(lds + Vo + tid * 4) = mv * (1.f / sqrtf(n2));
            } else {
                float pr = (*(const float*)(lds + Vo + tid * 4)) * mv;   // Rayleigh
                #pragma unroll
                for (int off = 32; off >= 1; off >>= 1) pr += __shfl_xor(pr, off);
                if (tid == 0) {
                    float L = 2.f * pr;                    // lambda(Q)=2*lambda(M)
                    scal[0] = 1.f / L;
                    scal[1] = LAMBDAV / L;
                }
            }
        }
    }
    __syncthreads();   // pow done; M/WC/v regions dead from here on

    const float c2  = 2.f * scal[0];
    const float thr = scal[1];

    // ---- WH plane: W-hi [256][64] bf16 (vectorized, init-once) ----
    #pragma unroll
    for (int i = 0; i < 16; ++i) {
        int i2 = tid + i * NTH;                   // f32x4 index over [256][64]
        int j = i2 >> 4, k4 = (i2 & 15) * 4;
        f32x4 v = *(const f32x4*)&Wg[j * 64 + k4];
        unsigned short h0 = __builtin_bit_cast(unsigned short, (__bf16)v.x);
        unsigned short h1 = __builtin_bit_cast(unsigned short, (__bf16)v.y);
        unsigned short h2 = __builtin_bit_cast(unsigned short, (__bf16)v.z);
        unsigned short h3 = __builtin_bit_cast(unsigned short, (__bf16)v.w);
        uint2 P; P.x = h0 | ((unsigned)h1 << 16); P.y = h2 | ((unsigned)h3 << 16);
        *(uint2*)(lds + WHo + j * 128 + ((k4 * 2) ^ ((j & 7) << 4))) = P;
    }

    // ---- p1 B-frags: W[32c+8l4+t][16w+ln] hi+lo -> 16 frags (64 VGPR) ----
    bf16x8 wbh[8], wbl[8];
    #pragma unroll
    for (int c = 0; c < 8; ++c) {
        bf16x8 ph{}, pl{};
        #pragma unroll
        for (int t = 0; t < 8; ++t) {
            float wv = Wg[(32 * c + 8 * l4 + t) * 64 + 16 * w + ln];
            __bf16 h = (__bf16)wv;
            ph[t] = h; pl[t] = (__bf16)(wv - (float)h);
        }
        wbh[c] = ph; wbl[c] = pl;
    }

    // ---- per-thread constants (2 m-tiles) ----
    float nin[2][4];
    #pragma unroll
    for (int s = 0; s < 2; ++s)
        #pragma unroll
        for (int r = 0; r < 4; ++r)
            nin[s][r] = -inp[(size_t)(rb + s * 16 + 4 * l4 + r) * 64 + 16 * w + ln];

    // ---- X0 -> xm/ym regs + y0-hi into YH (8 (dt,rt) tiles) ----
    float xm[4][2][4], ym[4][2][4];
    #pragma unroll
    for (int dt = 0; dt < 4; ++dt)
      #pragma unroll
      for (int rt = 0; rt < 2; ++rt) {
          f32x4 x = *(const f32x4*)&X0[(size_t)(rb + 16 * rt + ln) * 256 + (4 * w + dt) * 16 + 4 * l4];
          unsigned short hb[4];
          #pragma unroll
          for (int r = 0; r < 4; ++r) {
              xm[dt][rt][r] = x[r]; ym[dt][rt][r] = x[r];
              hb[r] = __builtin_bit_cast(unsigned short, (__bf16)x[r]);
          }
          const int row = 16 * rt + ln;
          const int off = row * 512 + ((((4 * w + dt) * 16 + 4 * l4) * 2) ^ rxl);
          uint2 H; H.x = hb[0] | ((unsigned)hb[1] << 16); H.y = hb[2] | ((unsigned)hb[3] << 16);
          *(uint2*)(lds + YHo + off) = H;
      }
    __syncthreads();

    float tt_ = 1.f;
    for (int step = 0; step < NSTEPS; ++step) {
        // ==== phase 1: R = y_h W - in  (2 m-tiles; W-frags reused 2x) ====
        f32x4 a0A = { nin[0][0], nin[0][1], nin[0][2], nin[0][3] };
        f32x4 a0C = { 0.f, 0.f, 0.f, 0.f };
        f32x4 a1A = { nin[1][0], nin[1][1], nin[1][2], nin[1][3] };
        f32x4 a1C = { 0.f, 0.f, 0.f, 0.f };
        #pragma unroll
        for (int c = 0; c < 8; ++c) {
            const int kb = c * 64 + l4 * 16;
            bf16x8 ah0 = *(const bf16x8*)(lds + YHo + ln * 512 + (kb ^ rxl));
            bf16x8 ah1 = *(const bf16x8*)(lds + YHo + (16 + ln) * 512 + (kb ^ rxl));
            a0A = __builtin_amdgcn_mfma_f32_16x16x32_bf16(ah0, wbh[c], a0A, 0, 0, 0);
            a0C = __builtin_amdgcn_mfma_f32_16x16x32_bf16(ah0, wbl[c], a0C, 0, 0, 0);
            a1A = __builtin_amdgcn_mfma_f32_16x16x32_bf16(ah1, wbh[c], a1A, 0, 0, 0);
            a1C = __builtin_amdgcn_mfma_f32_16x16x32_bf16(ah1, wbl[c], a1C, 0, 0, 0);
        }
        f32x4 acc0 = a0A + a0C;
        f32x4 acc1 = a1A + a1C;
        #pragma unroll
        for (int s = 0; s < 2; ++s) {
            #pragma unroll
            for (int r = 0; r < 4; ++r) {
                int row = s * 16 + 4 * l4 + r;
                int off = row * 128 + (((16 * w + ln) * 2) ^ ((row & 7) << 4));
                float v = s ? acc1[r] : acc0[r];
                __bf16 h = (__bf16)v;
                *(__bf16*)(lds + RHo + off) = h;
                *(__bf16*)(lds + RLo + off) = (__bf16)(v - (float)h);
            }
        }
        __syncthreads();

        // ==== phase 2: g^T = Wh R^T (4 dout x 2 row-tiles; WH reused 2x) ====
        f32x4 gt[4][2];
        #pragma unroll
        for (int dt = 0; dt < 4; ++dt)
            #pragma unroll
            for (int rt = 0; rt < 2; ++rt) gt[dt][rt] = (f32x4){0.f, 0.f, 0.f, 0.f};
        #pragma unroll
        for (int kc = 0; kc < 2; ++kc) {
            const int kb = kc * 64 + l4 * 16;
            bf16x8 bh[2], bl[2];
            #pragma unroll
            for (int rt = 0; rt < 2; ++rt) {
                bh[rt] = *(const bf16x8*)(lds + RHo + (16 * rt + ln) * 128 + (kb ^ rxl));
                bl[rt] = *(const bf16x8*)(lds + RLo + (16 * rt + ln) * 128 + (kb ^ rxl));
            }
            #pragma unroll
            for (int dt = 0; dt < 4; ++dt) {
                const int row = (4 * w + dt) * 16 + ln;       // row&7 == ln&7
                bf16x8 ah2 = *(const bf16x8*)(lds + WHo + row * 128 + (kb ^ rxl));
                #pragma unroll
                for (int rt = 0; rt < 2; ++rt) {
                    gt[dt][rt] = __builtin_amdgcn_mfma_f32_16x16x32_bf16(ah2, bh[rt], gt[dt][rt], 0, 0, 0);
                    gt[dt][rt] = __builtin_amdgcn_mfma_f32_16x16x32_bf16(ah2, bl[rt], gt[dt][rt], 0, 0, 0);
                }
            }
        }

        // ==== update: prox + momentum (fp32 ym in regs); y-hi b64 writes ====
        const float t2v = 0.5f + 0.5f * sqrtf(1.f + 4.f * tt_ * tt_);
        const float mom = (tt_ - 1.f) / t2v;
        tt_ = t2v;
        #pragma unroll
        for (int dt = 0; dt < 4; ++dt)
          #pragma unroll
          for (int rt = 0; rt < 2; ++rt) {
              unsigned short hb[4];
              #pragma unroll
              for (int r = 0; r < 4; ++r) {
                  float u  = ym[dt][rt][r] - c2 * gt[dt][rt][r];
                  float x2 = u - fminf(fmaxf(u, -thr), thr);    // prox (exact)
                  float yn = x2 + mom * (x2 - xm[dt][rt][r]);
                  xm[dt][rt][r] = x2; ym[dt][rt][r] = yn;
                  hb[r] = __builtin_bit_cast(unsigned short, (__bf16)yn);
              }
              const int row = 16 * rt + ln;
              const int off = row * 512 + ((((4 * w + dt) * 16 + 4 * l4) * 2) ^ rxl);
              uint2 H; H.x = hb[0] | ((unsigned)hb[1] << 16); H.y = hb[2] | ((unsigned)hb[3] << 16);
              *(uint2*)(lds + YHo + off) = H;
          }
        __syncthreads();
    }

    // ---- store X (float4) ----
    #pragma unroll
    for (int dt = 0; dt < 4; ++dt)
      #pragma unroll
      for (int rt = 0; rt < 2; ++rt) {
          f32x4 o = { xm[dt][rt][0], xm[dt][rt][1], xm[dt][rt][2], xm[dt][rt][3] };
          *(f32x4*)&out[(size_t)(rb + 16 * rt + ln) * 256 + (4 * w + dt) * 16 + 4 * l4] = o;
      }
}

extern "C" void kernel_launch(void* const* d_in, const int* in_sizes, int n_in,
                              void* d_out, int out_size, void* d_ws, size_t ws_size,
                              hipStream_t stream) {
    (void)in_sizes; (void)n_in; (void)d_ws; (void)ws_size; (void)out_size;
    const float* inp = (const float*)d_in[0];   // [16384, 64]
    const float* Wg  = (const float*)d_in[1];   // [256, 64]
    const float* X0  = (const float*)d_in[2];   // [16384, 256]
    float* outp      = (float*)d_out;           // [16384, 256]
    fista16<<<16384 / ROWS, NTH, 0, stream>>>(inp, Wg, X0, outp);
}

// Round 17
// 249.281 us; speedup vs baseline: 2.1108x; 1.1689x over previous
//
#include <hip/hip_runtime.h>
#include <hip/hip_bf16.h>

#define NTH     256
#define ROWS    32
#define NSTEPS  100
#define PITERS  50
#define LAMBDAV 0.1f

typedef __bf16 bf16x8 __attribute__((ext_vector_type(8)));
typedef float  f32x4  __attribute__((ext_vector_type(4)));

// R17 = R16 champion (291us) + p2 R-lo product dropped (RL plane deleted).
// Error anchor: R14's symmetric W-lo drop cost +0.031 absmax; predict
// 0.09-0.13 vs 0.15 threshold. Gains: p2 MFMA -50%, R writes halved
// (the 4-way-conflict b16 writes), p2 reads 16->12 b128, LDS -4KB.
// LDS map (53504 B, 2 blocks/CU uniform, grid 512 = one round, no tail):
//   YH bf16 [32][256] @0     (16384) stride 512
//   RH bf16 [32][64]  @16384 (4096)  stride 128
//   WH bf16 [256][64] @20480 (32768) stride 128
//   init overlays: WC/M fp32 [64][64] @0 (16KB, inside YH); v fp32[64] @53248
// Persistent regs ~136: wbh 32 + wbl 32 + xm 32 + ym 32 + nin 8.
#define YHo 0
#define RHo 16384
#define WHo 20480
#define WCo 0
#define Mo  0
#define Vo  53248

__global__ __launch_bounds__(NTH, 2)
void fista17(const float* __restrict__ inp, const float* __restrict__ Wg,
             const float* __restrict__ X0, float* __restrict__ out)
{
    __shared__ __align__(16) char lds[53504];
    __shared__ float scal[2];

    const int tid  = threadIdx.x;
    const int w    = tid >> 6;        // 0..3
    const int lane = tid & 63;
    const int l4   = lane >> 4;       // 0..3
    const int ln   = lane & 15;       // 0..15
    const int rb   = blockIdx.x * ROWS;
    const int rxl  = (ln & 7) << 4;

    // ================= M = W^T W  (4 chunks of 64 W-rows) =================
    {
        const int mi_ = tid >> 4;     // M rows 4mi_..4mi_+3
        const int mj_ = tid & 15;     // M cols 4mj_..4mj_+3
        f32x4 mac[4];
        #pragma unroll
        for (int r = 0; r < 4; ++r) mac[r] = (f32x4){0.f, 0.f, 0.f, 0.f};
        for (int ch = 0; ch < 4; ++ch) {
            #pragma unroll
            for (int i = 0; i < 4; ++i) {
                int idx = tid + i * NTH;               // f32x4 index, 0..1023
                int kl = idx >> 4, c4 = (idx & 15) * 4;
                f32x4 v = *(const f32x4*)&Wg[(64 * ch + kl) * 64 + c4];
                *(f32x4*)(lds + WCo + kl * 256 + ((c4 * 4) ^ ((kl & 7) << 4))) = v;
            }
            __syncthreads();
            #pragma unroll 8
            for (int k = 0; k < 64; ++k) {
                f32x4 a = *(const f32x4*)(lds + WCo + k * 256 + ((mi_ * 16) ^ ((k & 7) << 4)));
                f32x4 b = *(const f32x4*)(lds + WCo + k * 256 + ((mj_ * 16) ^ ((k & 7) << 4)));
                #pragma unroll
                for (int r = 0; r < 4; ++r) mac[r] += b * a[r];
            }
            __syncthreads();          // WC chunk consumed (last iter: WC dead)
        }
        #pragma unroll
        for (int r = 0; r < 4; ++r) {
            int m = 4 * mi_ + r;
            *(f32x4*)(lds + Mo + m * 256 + ((mj_ * 16) ^ ((m & 7) << 4))) = mac[r];
        }
    }
    __syncthreads();

    // ====== power iteration on M (wave 0; M read from LDS) ======
    if (tid < 64) {
        const int xsw = (tid & 7) << 4;
        *(float*)(lds + Vo + tid * 4) = 0.125f;            // ones(64)/8
        for (int it = 0; it <= PITERS; ++it) {
            float a0 = 0.f, a1 = 0.f, a2 = 0.f, a3 = 0.f;
            #pragma unroll
            for (int q = 0; q < 4; ++q) {
                f32x4 m0 = *(const f32x4*)(lds + Mo + tid * 256 + (((4 * q + 0) * 16) ^ xsw));
                f32x4 m1 = *(const f32x4*)(lds + Mo + tid * 256 + (((4 * q + 1) * 16) ^ xsw));
                f32x4 m2 = *(const f32x4*)(lds + Mo + tid * 256 + (((4 * q + 2) * 16) ^ xsw));
                f32x4 m3 = *(const f32x4*)(lds + Mo + tid * 256 + (((4 * q + 3) * 16) ^ xsw));
                f32x4 v0 = *(const f32x4*)(lds + Vo + (4 * q + 0) * 16);
                f32x4 v1 = *(const f32x4*)(lds + Vo + (4 * q + 1) * 16);
                f32x4 v2 = *(const f32x4*)(lds + Vo + (4 * q + 2) * 16);
                f32x4 v3 = *(const f32x4*)(lds + Vo + (4 * q + 3) * 16);
                a0 += m0.x * v0.x + m0.y * v0.y + m0.z * v0.z + m0.w * v0.w;
                a1 += m1.x * v1.x + m1.y * v1.y + m1.z * v1.z + m1.w * v1.w;
                a2 += m2.x * v2.x + m2.y * v2.y + m2.z * v2.z + m2.w * v2.w;
                a3 += m3.x * v3.x + m3.y * v3.y + m3.z * v3.z + m3.w * v3.w;
            }
            float mv = (a0 + a1) + (a2 + a3);               // (M v)[tid]
            if (it < PITERS) {
                float n2 = mv * mv;
                #pragma unroll
                for (int off = 32; off >= 1; off >>= 1) n2 += __shfl_xor(n2, off);
                *(float*)(lds + Vo + tid * 4) = mv * (1.f / sqrtf(n2));
            } else {
                float pr = (*(const float*)(lds + Vo + tid * 4)) * mv;   // Rayleigh
                #pragma unroll
                for (int off = 32; off >= 1; off >>= 1) pr += __shfl_xor(pr, off);
                if (tid == 0) {
                    float L = 2.f * pr;                    // lambda(Q)=2*lambda(M)
                    scal[0] = 1.f / L;
                    scal[1] = LAMBDAV / L;
                }
            }
        }
    }
    __syncthreads();   // pow done; M/WC/v regions dead from here on

    const float c2  = 2.f * scal[0];
    const float thr = scal[1];

    // ---- WH plane: W-hi [256][64] bf16 (vectorized, init-once) ----
    #pragma unroll
    for (int i = 0; i < 16; ++i) {
        int i2 = tid + i * NTH;                   // f32x4 index over [256][64]
        int j = i2 >> 4, k4 = (i2 & 15) * 4;
        f32x4 v = *(const f32x4*)&Wg[j * 64 + k4];
        unsigned short h0 = __builtin_bit_cast(unsigned short, (__bf16)v.x);
        unsigned short h1 = __builtin_bit_cast(unsigned short, (__bf16)v.y);
        unsigned short h2 = __builtin_bit_cast(unsigned short, (__bf16)v.z);
        unsigned short h3 = __builtin_bit_cast(unsigned short, (__bf16)v.w);
        uint2 P; P.x = h0 | ((unsigned)h1 << 16); P.y = h2 | ((unsigned)h3 << 16);
        *(uint2*)(lds + WHo + j * 128 + ((k4 * 2) ^ ((j & 7) << 4))) = P;
    }

    // ---- p1 B-frags: W[32c+8l4+t][16w+ln] hi+lo -> 16 frags (64 VGPR) ----
    bf16x8 wbh[8], wbl[8];
    #pragma unroll
    for (int c = 0; c < 8; ++c) {
        bf16x8 ph{}, pl{};
        #pragma unroll
        for (int t = 0; t < 8; ++t) {
            float wv = Wg[(32 * c + 8 * l4 + t) * 64 + 16 * w + ln];
            __bf16 h = (__bf16)wv;
            ph[t] = h; pl[t] = (__bf16)(wv - (float)h);
        }
        wbh[c] = ph; wbl[c] = pl;
    }

    // ---- per-thread constants (2 m-tiles) ----
    float nin[2][4];
    #pragma unroll
    for (int s = 0; s < 2; ++s)
        #pragma unroll
        for (int r = 0; r < 4; ++r)
            nin[s][r] = -inp[(size_t)(rb + s * 16 + 4 * l4 + r) * 64 + 16 * w + ln];

    // ---- X0 -> xm/ym regs + y0-hi into YH (8 (dt,rt) tiles) ----
    float xm[4][2][4], ym[4][2][4];
    #pragma unroll
    for (int dt = 0; dt < 4; ++dt)
      #pragma unroll
      for (int rt = 0; rt < 2; ++rt) {
          f32x4 x = *(const f32x4*)&X0[(size_t)(rb + 16 * rt + ln) * 256 + (4 * w + dt) * 16 + 4 * l4];
          unsigned short hb[4];
          #pragma unroll
          for (int r = 0; r < 4; ++r) {
              xm[dt][rt][r] = x[r]; ym[dt][rt][r] = x[r];
              hb[r] = __builtin_bit_cast(unsigned short, (__bf16)x[r]);
          }
          const int row = 16 * rt + ln;
          const int off = row * 512 + ((((4 * w + dt) * 16 + 4 * l4) * 2) ^ rxl);
          uint2 H; H.x = hb[0] | ((unsigned)hb[1] << 16); H.y = hb[2] | ((unsigned)hb[3] << 16);
          *(uint2*)(lds + YHo + off) = H;
      }
    __syncthreads();

    float tt_ = 1.f;
    for (int step = 0; step < NSTEPS; ++step) {
        // ==== phase 1: R = y_h W - in  (2 m-tiles; W-frags reused 2x) ====
        f32x4 a0A = { nin[0][0], nin[0][1], nin[0][2], nin[0][3] };
        f32x4 a0C = { 0.f, 0.f, 0.f, 0.f };
        f32x4 a1A = { nin[1][0], nin[1][1], nin[1][2], nin[1][3] };
        f32x4 a1C = { 0.f, 0.f, 0.f, 0.f };
        #pragma unroll
        for (int c = 0; c < 8; ++c) {
            const int kb = c * 64 + l4 * 16;
            bf16x8 ah0 = *(const bf16x8*)(lds + YHo + ln * 512 + (kb ^ rxl));
            bf16x8 ah1 = *(const bf16x8*)(lds + YHo + (16 + ln) * 512 + (kb ^ rxl));
            a0A = __builtin_amdgcn_mfma_f32_16x16x32_bf16(ah0, wbh[c], a0A, 0, 0, 0);
            a0C = __builtin_amdgcn_mfma_f32_16x16x32_bf16(ah0, wbl[c], a0C, 0, 0, 0);
            a1A = __builtin_amdgcn_mfma_f32_16x16x32_bf16(ah1, wbh[c], a1A, 0, 0, 0);
            a1C = __builtin_amdgcn_mfma_f32_16x16x32_bf16(ah1, wbl[c], a1C, 0, 0, 0);
        }
        f32x4 acc0 = a0A + a0C;
        f32x4 acc1 = a1A + a1C;
        #pragma unroll
        for (int s = 0; s < 2; ++s) {
            #pragma unroll
            for (int r = 0; r < 4; ++r) {
                int row = s * 16 + 4 * l4 + r;
                int off = row * 128 + (((16 * w + ln) * 2) ^ ((row & 7) << 4));
                float v = s ? acc1[r] : acc0[r];
                *(__bf16*)(lds + RHo + off) = (__bf16)v;
            }
        }
        __syncthreads();

        // ==== phase 2: g^T = Wh Rh^T (4 dout x 2 row-tiles; WH reused 2x) ====
        f32x4 gt[4][2];
        #pragma unroll
        for (int dt = 0; dt < 4; ++dt)
            #pragma unroll
            for (int rt = 0; rt < 2; ++rt) gt[dt][rt] = (f32x4){0.f, 0.f, 0.f, 0.f};
        #pragma unroll
        for (int kc = 0; kc < 2; ++kc) {
            const int kb = kc * 64 + l4 * 16;
            bf16x8 bh[2];
            #pragma unroll
            for (int rt = 0; rt < 2; ++rt)
                bh[rt] = *(const bf16x8*)(lds + RHo + (16 * rt + ln) * 128 + (kb ^ rxl));
            #pragma unroll
            for (int dt = 0; dt < 4; ++dt) {
                const int row = (4 * w + dt) * 16 + ln;       // row&7 == ln&7
                bf16x8 ah2 = *(const bf16x8*)(lds + WHo + row * 128 + (kb ^ rxl));
                #pragma unroll
                for (int rt = 0; rt < 2; ++rt)
                    gt[dt][rt] = __builtin_amdgcn_mfma_f32_16x16x32_bf16(ah2, bh[rt], gt[dt][rt], 0, 0, 0);
            }
        }

        // ==== update: prox + momentum (fp32 ym in regs); y-hi b64 writes ====
        const float t2v = 0.5f + 0.5f * sqrtf(1.f + 4.f * tt_ * tt_);
        const float mom = (tt_ - 1.f) / t2v;
        tt_ = t2v;
        #pragma unroll
        for (int dt = 0; dt < 4; ++dt)
          #pragma unroll
          for (int rt = 0; rt < 2; ++rt) {
              unsigned short hb[4];
              #pragma unroll
              for (int r = 0; r < 4; ++r) {
                  float u  = ym[dt][rt][r] - c2 * gt[dt][rt][r];
                  float x2 = u - fminf(fmaxf(u, -thr), thr);    // prox (exact)
                  float yn = x2 + mom * (x2 - xm[dt][rt][r]);
                  xm[dt][rt][r] = x2; ym[dt][rt][r] = yn;
                  hb[r] = __builtin_bit_cast(unsigned short, (__bf16)yn);
              }
              const int row = 16 * rt + ln;
              const int off = row * 512 + ((((4 * w + dt) * 16 + 4 * l4) * 2) ^ rxl);
              uint2 H; H.x = hb[0] | ((unsigned)hb[1] << 16); H.y = hb[2] | ((unsigned)hb[3] << 16);
              *(uint2*)(lds + YHo + off) = H;
          }
        __syncthreads();
    }

    // ---- store X (float4) ----
    #pragma unroll
    for (int dt = 0; dt < 4; ++dt)
      #pragma unroll
      for (int rt = 0; rt < 2; ++rt) {
          f32x4 o = { xm[dt][rt][0], xm[dt][rt][1], xm[dt][rt][2], xm[dt][rt][3] };
          *(f32x4*)&out[(size_t)(rb + 16 * rt + ln) * 256 + (4 * w + dt) * 16 + 4 * l4] = o;
      }
}

extern "C" void kernel_launch(void* const* d_in, const int* in_sizes, int n_in,
                              void* d_out, int out_size, void* d_ws, size_t ws_size,
                              hipStream_t stream) {
    (void)in_sizes; (void)n_in; (void)d_ws; (void)ws_size; (void)out_size;
    const float* inp = (const float*)d_in[0];   // [16384, 64]
    const float* Wg  = (const float*)d_in[1];   // [256, 64]
    const float* X0  = (const float*)d_in[2];   // [16384, 256]
    float* outp      = (float*)d_out;           // [16384, 256]
    fista17<<<16384 / ROWS, NTH, 0, stream>>>(inp, Wg, X0, outp);
}

// Round 18
// 223.236 us; speedup vs baseline: 2.3571x; 1.1167x over previous
//
#include <hip/hip_runtime.h>
#include <hip/hip_bf16.h>

#define NTH     256
#define ROWS    32
#define NSTEPS  100
#define PITERS  50
#define LAMBDAV 0.1f

typedef __bf16 bf16x8 __attribute__((ext_vector_type(8)));
typedef float  f32x4  __attribute__((ext_vector_type(4)));

// R18 = R17 + (1) p1 operand-swap: R^T = mfma(W-frag as A, y-frag as B).
//   EXACT: wbh bytes and y-reads are identical under the swap (A/B frags share
//   the lane->element map); only D-layout flips -> thread owns R[s16+ln][4
//   consecutive cols] -> R-writes become 2 packed b64 (was 8 scalar b16 with
//   4-way bank conflicts); nin becomes f32x4 loads from in^T.
// (2) p1 W-lo product dropped (wbl deleted): p1 MFMA 32->16/wave-step.
//   Anchor: R14's symmetric drop doubled absmax (0.031->0.0625); R13/R17
//   drops were free. Predict 0.09-0.125 vs 0.15. If FAIL: restore wbl only.
// LDS map (53504 B, 2 blocks/CU uniform, grid 512, one round, no tail):
//   YH bf16 [32][256] @0     (16384) stride 512
//   RH bf16 [32][64]  @16384 (4096)  stride 128
//   WH bf16 [256][64] @20480 (32768) stride 128
//   init overlays: WC/M fp32 [64][64] @0 (16KB, inside YH); v fp32[64] @53248
// Persistent regs ~104: wbh 32 + xm 32 + ym 32 + nin 8.
#define YHo 0
#define RHo 16384
#define WHo 20480
#define WCo 0
#define Mo  0
#define Vo  53248

__global__ __launch_bounds__(NTH, 2)
void fista18(const float* __restrict__ inp, const float* __restrict__ Wg,
             const float* __restrict__ X0, float* __restrict__ out)
{
    __shared__ __align__(16) char lds[53504];
    __shared__ float scal[2];

    const int tid  = threadIdx.x;
    const int w    = tid >> 6;        // 0..3
    const int lane = tid & 63;
    const int l4   = lane >> 4;       // 0..3
    const int ln   = lane & 15;       // 0..15
    const int rb   = blockIdx.x * ROWS;
    const int rxl  = (ln & 7) << 4;

    // ================= M = W^T W  (4 chunks of 64 W-rows) =================
    {
        const int mi_ = tid >> 4;     // M rows 4mi_..4mi_+3
        const int mj_ = tid & 15;     // M cols 4mj_..4mj_+3
        f32x4 mac[4];
        #pragma unroll
        for (int r = 0; r < 4; ++r) mac[r] = (f32x4){0.f, 0.f, 0.f, 0.f};
        for (int ch = 0; ch < 4; ++ch) {
            #pragma unroll
            for (int i = 0; i < 4; ++i) {
                int idx = tid + i * NTH;               // f32x4 index, 0..1023
                int kl = idx >> 4, c4 = (idx & 15) * 4;
                f32x4 v = *(const f32x4*)&Wg[(64 * ch + kl) * 64 + c4];
                *(f32x4*)(lds + WCo + kl * 256 + ((c4 * 4) ^ ((kl & 7) << 4))) = v;
            }
            __syncthreads();
            #pragma unroll 8
            for (int k = 0; k < 64; ++k) {
                f32x4 a = *(const f32x4*)(lds + WCo + k * 256 + ((mi_ * 16) ^ ((k & 7) << 4)));
                f32x4 b = *(const f32x4*)(lds + WCo + k * 256 + ((mj_ * 16) ^ ((k & 7) << 4)));
                #pragma unroll
                for (int r = 0; r < 4; ++r) mac[r] += b * a[r];
            }
            __syncthreads();          // WC chunk consumed (last iter: WC dead)
        }
        #pragma unroll
        for (int r = 0; r < 4; ++r) {
            int m = 4 * mi_ + r;
            *(f32x4*)(lds + Mo + m * 256 + ((mj_ * 16) ^ ((m & 7) << 4))) = mac[r];
        }
    }
    __syncthreads();

    // ====== power iteration on M (wave 0; M read from LDS) ======
    if (tid < 64) {
        const int xsw = (tid & 7) << 4;
        *(float*)(lds + Vo + tid * 4) = 0.125f;            // ones(64)/8
        for (int it = 0; it <= PITERS; ++it) {
            float a0 = 0.f, a1 = 0.f, a2 = 0.f, a3 = 0.f;
            #pragma unroll
            for (int q = 0; q < 4; ++q) {
                f32x4 m0 = *(const f32x4*)(lds + Mo + tid * 256 + (((4 * q + 0) * 16) ^ xsw));
                f32x4 m1 = *(const f32x4*)(lds + Mo + tid * 256 + (((4 * q + 1) * 16) ^ xsw));
                f32x4 m2 = *(const f32x4*)(lds + Mo + tid * 256 + (((4 * q + 2) * 16) ^ xsw));
                f32x4 m3 = *(const f32x4*)(lds + Mo + tid * 256 + (((4 * q + 3) * 16) ^ xsw));
                f32x4 v0 = *(const f32x4*)(lds + Vo + (4 * q + 0) * 16);
                f32x4 v1 = *(const f32x4*)(lds + Vo + (4 * q + 1) * 16);
                f32x4 v2 = *(const f32x4*)(lds + Vo + (4 * q + 2) * 16);
                f32x4 v3 = *(const f32x4*)(lds + Vo + (4 * q + 3) * 16);
                a0 += m0.x * v0.x + m0.y * v0.y + m0.z * v0.z + m0.w * v0.w;
                a1 += m1.x * v1.x + m1.y * v1.y + m1.z * v1.z + m1.w * v1.w;
                a2 += m2.x * v2.x + m2.y * v2.y + m2.z * v2.z + m2.w * v2.w;
                a3 += m3.x * v3.x + m3.y * v3.y + m3.z * v3.z + m3.w * v3.w;
            }
            float mv = (a0 + a1) + (a2 + a3);               // (M v)[tid]
            if (it < PITERS) {
                float n2 = mv * mv;
                #pragma unroll
                for (int off = 32; off >= 1; off >>= 1) n2 += __shfl_xor(n2, off);
                *(float*)(lds + Vo + tid * 4) = mv * (1.f / sqrtf(n2));
            } else {
                float pr = (*(const float*)(lds + Vo + tid * 4)) * mv;   // Rayleigh
                #pragma unroll
                for (int off = 32; off >= 1; off >>= 1) pr += __shfl_xor(pr, off);
                if (tid == 0) {
                    float L = 2.f * pr;                    // lambda(Q)=2*lambda(M)
                    scal[0] = 1.f / L;
                    scal[1] = LAMBDAV / L;
                }
            }
        }
    }
    __syncthreads();   // pow done; M/WC/v regions dead from here on

    const float c2  = 2.f * scal[0];
    const float thr = scal[1];

    // ---- WH plane: W-hi [256][64] bf16 (vectorized, init-once) ----
    #pragma unroll
    for (int i = 0; i < 16; ++i) {
        int i2 = tid + i * NTH;                   // f32x4 index over [256][64]
        int j = i2 >> 4, k4 = (i2 & 15) * 4;
        f32x4 v = *(const f32x4*)&Wg[j * 64 + k4];
        unsigned short h0 = __builtin_bit_cast(unsigned short, (__bf16)v.x);
        unsigned short h1 = __builtin_bit_cast(unsigned short, (__bf16)v.y);
        unsigned short h2 = __builtin_bit_cast(unsigned short, (__bf16)v.z);
        unsigned short h3 = __builtin_bit_cast(unsigned short, (__bf16)v.w);
        uint2 P; P.x = h0 | ((unsigned)h1 << 16); P.y = h2 | ((unsigned)h3 << 16);
        *(uint2*)(lds + WHo + j * 128 + ((k4 * 2) ^ ((j & 7) << 4))) = P;
    }

    // ---- p1 W frags (hi only): W[32c+8l4+t][16w+ln] -> 8 frags (32 VGPR) ----
    // Used as the A-operand of the swapped MFMA (A-frag map == B-frag map).
    bf16x8 wbh[8];
    #pragma unroll
    for (int c = 0; c < 8; ++c) {
        bf16x8 ph{};
        #pragma unroll
        for (int t = 0; t < 8; ++t)
            ph[t] = (__bf16)Wg[(32 * c + 8 * l4 + t) * 64 + 16 * w + ln];
        wbh[c] = ph;
    }

    // ---- per-thread constants: -in in the R^T D-layout (f32x4 loads) ----
    float nin[2][4];
    #pragma unroll
    for (int s = 0; s < 2; ++s) {
        f32x4 iv = *(const f32x4*)&inp[(size_t)(rb + s * 16 + ln) * 64 + 16 * w + 4 * l4];
        #pragma unroll
        for (int r = 0; r < 4; ++r) nin[s][r] = -iv[r];
    }

    // ---- X0 -> xm/ym regs + y0-hi into YH (8 (dt,rt) tiles) ----
    float xm[4][2][4], ym[4][2][4];
    #pragma unroll
    for (int dt = 0; dt < 4; ++dt)
      #pragma unroll
      for (int rt = 0; rt < 2; ++rt) {
          f32x4 x = *(const f32x4*)&X0[(size_t)(rb + 16 * rt + ln) * 256 + (4 * w + dt) * 16 + 4 * l4];
          unsigned short hb[4];
          #pragma unroll
          for (int r = 0; r < 4; ++r) {
              xm[dt][rt][r] = x[r]; ym[dt][rt][r] = x[r];
              hb[r] = __builtin_bit_cast(unsigned short, (__bf16)x[r]);
          }
          const int row = 16 * rt + ln;
          const int off = row * 512 + ((((4 * w + dt) * 16 + 4 * l4) * 2) ^ rxl);
          uint2 H; H.x = hb[0] | ((unsigned)hb[1] << 16); H.y = hb[2] | ((unsigned)hb[3] << 16);
          *(uint2*)(lds + YHo + off) = H;
      }
    __syncthreads();

    float tt_ = 1.f;
    for (int step = 0; step < NSTEPS; ++step) {
        // ==== phase 1 (swapped): R^T tiles = W^T(n-tile w) x y^T(m-tile s) ====
        // 4 accumulation chains (2 per m-tile) for ILP; exact same products.
        f32x4 r0e = { nin[0][0], nin[0][1], nin[0][2], nin[0][3] };
        f32x4 r1e = { nin[1][0], nin[1][1], nin[1][2], nin[1][3] };
        f32x4 r0o = { 0.f, 0.f, 0.f, 0.f };
        f32x4 r1o = { 0.f, 0.f, 0.f, 0.f };
        #pragma unroll
        for (int c = 0; c < 8; ++c) {
            const int kb = c * 64 + l4 * 16;
            bf16x8 bh0 = *(const bf16x8*)(lds + YHo + ln * 512 + (kb ^ rxl));
            bf16x8 bh1 = *(const bf16x8*)(lds + YHo + (16 + ln) * 512 + (kb ^ rxl));
            if (c & 1) {
                r0o = __builtin_amdgcn_mfma_f32_16x16x32_bf16(wbh[c], bh0, r0o, 0, 0, 0);
                r1o = __builtin_amdgcn_mfma_f32_16x16x32_bf16(wbh[c], bh1, r1o, 0, 0, 0);
            } else {
                r0e = __builtin_amdgcn_mfma_f32_16x16x32_bf16(wbh[c], bh0, r0e, 0, 0, 0);
                r1e = __builtin_amdgcn_mfma_f32_16x16x32_bf16(wbh[c], bh1, r1e, 0, 0, 0);
            }
        }
        f32x4 acc0 = r0e + r0o;     // R[s=0 rows][cols 16w+4l4 .. +3] at row ln
        f32x4 acc1 = r1e + r1o;
        #pragma unroll
        for (int s = 0; s < 2; ++s) {
            f32x4 v = s ? acc1 : acc0;
            unsigned short hb[4];
            #pragma unroll
            for (int r = 0; r < 4; ++r)
                hb[r] = __builtin_bit_cast(unsigned short, (__bf16)v[r]);
            const int row = s * 16 + ln;
            const int off = row * 128 + (((16 * w + 4 * l4) * 2) ^ ((row & 7) << 4));
            uint2 H; H.x = hb[0] | ((unsigned)hb[1] << 16); H.y = hb[2] | ((unsigned)hb[3] << 16);
            *(uint2*)(lds + RHo + off) = H;
        }
        __syncthreads();

        // ==== phase 2: g^T = Wh Rh^T (4 dout x 2 row-tiles; WH reused 2x) ====
        f32x4 gt[4][2];
        #pragma unroll
        for (int dt = 0; dt < 4; ++dt)
            #pragma unroll
            for (int rt = 0; rt < 2; ++rt) gt[dt][rt] = (f32x4){0.f, 0.f, 0.f, 0.f};
        #pragma unroll
        for (int kc = 0; kc < 2; ++kc) {
            const int kb = kc * 64 + l4 * 16;
            bf16x8 bh[2];
            #pragma unroll
            for (int rt = 0; rt < 2; ++rt)
                bh[rt] = *(const bf16x8*)(lds + RHo + (16 * rt + ln) * 128 + (kb ^ rxl));
            #pragma unroll
            for (int dt = 0; dt < 4; ++dt) {
                const int row = (4 * w + dt) * 16 + ln;       // row&7 == ln&7
                bf16x8 ah2 = *(const bf16x8*)(lds + WHo + row * 128 + (kb ^ rxl));
                #pragma unroll
                for (int rt = 0; rt < 2; ++rt)
                    gt[dt][rt] = __builtin_amdgcn_mfma_f32_16x16x32_bf16(ah2, bh[rt], gt[dt][rt], 0, 0, 0);
            }
        }

        // ==== update: prox + momentum (fp32 ym in regs); y-hi b64 writes ====
        const float t2v = 0.5f + 0.5f * sqrtf(1.f + 4.f * tt_ * tt_);
        const float mom = (tt_ - 1.f) / t2v;
        tt_ = t2v;
        #pragma unroll
        for (int dt = 0; dt < 4; ++dt)
          #pragma unroll
          for (int rt = 0; rt < 2; ++rt) {
              unsigned short hb[4];
              #pragma unroll
              for (int r = 0; r < 4; ++r) {
                  float u  = ym[dt][rt][r] - c2 * gt[dt][rt][r];
                  float x2 = u - fminf(fmaxf(u, -thr), thr);    // prox (exact)
                  float yn = x2 + mom * (x2 - xm[dt][rt][r]);
                  xm[dt][rt][r] = x2; ym[dt][rt][r] = yn;
                  hb[r] = __builtin_bit_cast(unsigned short, (__bf16)yn);
              }
              const int row = 16 * rt + ln;
              const int off = row * 512 + ((((4 * w + dt) * 16 + 4 * l4) * 2) ^ rxl);
              uint2 H; H.x = hb[0] | ((unsigned)hb[1] << 16); H.y = hb[2] | ((unsigned)hb[3] << 16);
              *(uint2*)(lds + YHo + off) = H;
          }
        __syncthreads();
    }

    // ---- store X (float4) ----
    #pragma unroll
    for (int dt = 0; dt < 4; ++dt)
      #pragma unroll
      for (int rt = 0; rt < 2; ++rt) {
          f32x4 o = { xm[dt][rt][0], xm[dt][rt][1], xm[dt][rt][2], xm[dt][rt][3] };
          *(f32x4*)&out[(size_t)(rb + 16 * rt + ln) * 256 + (4 * w + dt) * 16 + 4 * l4] = o;
      }
}

extern "C" void kernel_launch(void* const* d_in, const int* in_sizes, int n_in,
                              void* d_out, int out_size, void* d_ws, size_t ws_size,
                              hipStream_t stream) {
    (void)in_sizes; (void)n_in; (void)d_ws; (void)ws_size; (void)out_size;
    const float* inp = (const float*)d_in[0];   // [16384, 64]
    const float* Wg  = (const float*)d_in[1];   // [256, 64]
    const float* X0  = (const float*)d_in[2];   // [16384, 256]
    float* outp      = (float*)d_out;           // [16384, 256]
    fista18<<<16384 / ROWS, NTH, 0, stream>>>(inp, Wg, X0, outp);
}